// Round 3
// baseline (300.778 us; speedup 1.0000x reference)
//
#include <hip/hip_runtime.h>
#include <hip/hip_fp16.h>

typedef _Float16 f16;
typedef _Float16 f16x8 __attribute__((ext_vector_type(8)));
typedef _Float16 f16x4 __attribute__((ext_vector_type(4)));
typedef _Float16 f16x2 __attribute__((ext_vector_type(2)));
typedef float f32x4 __attribute__((ext_vector_type(4)));

#define GLB(p) ((const __attribute__((address_space(1))) void*)(p))
#define LDSP(p) ((__attribute__((address_space(3))) void*)(p))

__device__ __forceinline__ void gload16(const void* g, void* l) {
  __builtin_amdgcn_global_load_lds(GLB(g), LDSP(l), 16, 0, 0);
}

// counted vmcnt wait (immediate) + compiler-fenced barrier
#define VMW(n) asm volatile("s_waitcnt vmcnt(" #n ")" ::: "memory")
__device__ __forceinline__ void barrier_fenced() {
  asm volatile("" ::: "memory");
  __builtin_amdgcn_s_barrier();
  asm volatile("" ::: "memory");
}

// ---------------- prep ----------------
__global__ __launch_bounds__(256) void prep_x(const float* __restrict__ x,
                                              f16* __restrict__ xb) {
  int i = (blockIdx.x * 256 + threadIdx.x) * 4;
  float4 v = *(const float4*)(x + i);
  f16x4 o = {(f16)v.x, (f16)v.y, (f16)v.z, (f16)v.w};
  *(f16x4*)(xb + i) = o;
}

// WT'[n'][c] = W[c][(n'&255)*8 + (n'>>8)]   (n' = h*256+d, src n = d*8+h)
// WoT'[dm][n'] = Wo[(d*8+h)*256 + dm]
__global__ __launch_bounds__(256) void prep_w(
    const float* __restrict__ Wq, const float* __restrict__ Wk,
    const float* __restrict__ Wv, const float* __restrict__ Wo,
    const float* __restrict__ bq, const float* __restrict__ bk,
    const float* __restrict__ bv,
    f16* __restrict__ WqT, f16* __restrict__ WkT, f16* __restrict__ WvT,
    f16* __restrict__ WoT, float* __restrict__ bqp, float* __restrict__ bkp,
    float* __restrict__ bvp) {
  int i = blockIdx.x * 256 + threadIdx.x;  // 0..524287
  {
    int np = i >> 8, c = i & 255;
    int src = c * 2048 + (np & 255) * 8 + (np >> 8);
    WqT[i] = (f16)Wq[src];
    WkT[i] = (f16)Wk[src];
    WvT[i] = (f16)Wv[src];
  }
  {
    int dm = i >> 11, np = i & 2047;
    WoT[i] = (f16)Wo[((np & 255) * 8 + (np >> 8)) * 256 + dm];
  }
  if (i < 2048) {
    int src = (i & 255) * 8 + (i >> 8);
    bqp[i] = bq[src];
    bkp[i] = bk[src];
    bvp[i] = bv[src];
  }
}

// ---------------- generic 128x128 fp16 GEMM, K-innermost operands ----------------
// 4-buffer pipeline, counted vmcnt (prefetch distance 2, top barrier).
// A(m,k) elem = (m>>8)*aq1 + (m&255)*256 + (k>>8)*aq3 + (k&255)
// B(n,k) elem = n*ldb + k
// C(m,n) elem = (m>>8)*cp1 + (m&255)*256 + (n>>8)*cp3 + (n&255)
// OUTMODE: 0 = f16 out + col bias, 1 = f16 out + row bias, 2 = f32 out + col bias
template <int OUTMODE>
__global__ __launch_bounds__(256, 4) void gemm128(
    const f16* __restrict__ A, const f16* __restrict__ B,
    const float* __restrict__ bias, void* __restrict__ Cptr, int K, int aq1,
    int aq3, int ldb, long cp1, long cp3) {
  __shared__ f16 As[4][128 * 32];
  __shared__ f16 Bs[4][128 * 32];
  const int tid = threadIdx.x;
  const int m0 = blockIdx.y * 128;
  const int n0 = blockIdx.x * 128;
  const int lane = tid & 63, wid = tid >> 6;
  const int l15 = lane & 15, lg = lane >> 4;
  const int wm = (wid >> 1) * 64, wn = (wid & 1) * 64;

  f32x4 acc[4][4] = {};

  auto stage = [&](int buf, int kt) {
    int k0 = kt * 32;
#pragma unroll
    for (int r = 0; r < 2; ++r) {
      int flat = r * 4096 + tid * 16;  // byte offset within 8KB tile
      int row = flat >> 6;             // 64B per row
      int kk = k0 + ((flat & 63) >> 1);
      int m = m0 + row;
      gload16(A + (long)(m >> 8) * aq1 + (long)(m & 255) * 256 +
                  (long)(kk >> 8) * aq3 + (kk & 255),
              (char*)(&As[buf][0]) + flat);
      int n = n0 + row;
      gload16(B + (long)n * ldb + kk, (char*)(&Bs[buf][0]) + flat);
    }
  };

  auto compute = [&](int t) {
    const f16* as = &As[t & 3][0];
    const f16* bs = &Bs[t & 3][0];
    f16x8 af[4], bf[4];
#pragma unroll
    for (int i = 0; i < 4; ++i)
      af[i] = *(const f16x8*)(as + (wm + i * 16 + l15) * 32 + lg * 8);
#pragma unroll
    for (int j = 0; j < 4; ++j)
      bf[j] = *(const f16x8*)(bs + (wn + j * 16 + l15) * 32 + lg * 8);
#pragma unroll
    for (int i = 0; i < 4; ++i)
#pragma unroll
      for (int j = 0; j < 4; ++j)
        acc[i][j] =
            __builtin_amdgcn_mfma_f32_16x16x32_f16(af[i], bf[j], acc[i][j], 0, 0, 0);
  };

  const int T = K >> 5;  // always >= 8
  stage(0, 0);
  stage(1, 1);
  for (int t = 0; t < T - 2; ++t) {
    stage((t + 2) & 3, t + 2);
    VMW(8);   // tiles {t+1, t+2} (4 loads each) may remain in flight
    barrier_fenced();
    compute(t);
  }
  VMW(4);  // only tile T-1 in flight
  barrier_fenced();
  compute(T - 2);
  VMW(0);
  barrier_fenced();
  compute(T - 1);

#pragma unroll
  for (int i = 0; i < 4; ++i) {
#pragma unroll
    for (int j = 0; j < 4; ++j) {
#pragma unroll
      for (int jj = 0; jj < 4; ++jj) {
        int m = m0 + wm + i * 16 + lg * 4 + jj;
        int n = n0 + wn + j * 16 + l15;
        float v = acc[i][j][jj];
        v += (OUTMODE == 1) ? bias[m] : bias[n];
        long off = (long)(m >> 8) * cp1 + (long)(m & 255) * 256 +
                   (long)(n >> 8) * cp3 + (n & 255);
        if (OUTMODE == 2)
          ((float*)Cptr)[off] = v;
        else
          ((f16*)Cptr)[off] = (f16)v;
      }
    }
  }
}

// ---------------- fused attention: one block per (bc,h), q-tile = 256 ----------------
// 512 threads = 8 waves; wave w owns q rows [w*32, w*32+32) (all LDS P rows/reads
// are wave-private -> no barriers around P).
// Q lives in registers (qf). K0..K7,V0..V7 stream as 16 tiles (16KB each) through
// 4 rotating LDS buffers with counted vmcnt (prefetch distance 2).
// LDS: P half [256 rows][128 cols] f16 swizzled @0 (64KB); tiles @65536 (4x16KB).
__global__ __launch_bounds__(512, 2) void attn_fused3(const f16* __restrict__ QK,
                                                      const f16* __restrict__ Vw,
                                                      f16* __restrict__ Ow) {
  __shared__ __align__(16) char smem[131072];
  const int tid = threadIdx.x;
  const int lane = tid & 63, wid = tid >> 6;
  const int l15 = lane & 15, lg = lane >> 4;
  const int h = blockIdx.x, bc = blockIdx.y;
  const long base = (long)bc * 1048576 + (long)h * 65536;  // Q slice in interleaved QK
  const f16* Qh = QK + base;
  const f16* Kh = QK + base + 524288;
  const f16* Vh = Vw + (long)bc * 524288 + (long)h * 65536;  // V^T [d][q]
  const int w32 = wid * 32;

  // ---- Q fragments straight to registers (consumed at MFMA time) ----
  f16x8 qf[2][8];
#pragma unroll
  for (int i = 0; i < 2; ++i)
#pragma unroll
    for (int t = 0; t < 8; ++t)
      qf[i][t] =
          *(const f16x8*)(Qh + (long)(w32 + i * 16 + l15) * 256 + t * 32 + lg * 8);

  // stage a [256 rows][32 k] tile (16KB) with source-side swizzle so physical
  // byte = row*64 + (colbytes ^ (((row>>1)&3)<<4)); LDS dest linear.
  auto stageT = [&](const f16* src, int buf, int kt) {
#pragma unroll
    for (int r = 0; r < 2; ++r) {
      int flat = r * 8192 + tid * 16;
      int row = flat >> 6;
      int kk = kt * 32 + (((flat ^ (((row >> 1) & 3) << 4)) & 63) >> 1);
      gload16(src + (long)row * 256 + kk, smem + 65536 + buf * 16384 + flat);
    }
  };
  auto ldfrag = [&](int buf, int row, int koff) -> f16x8 {
    return *(const f16x8*)(smem + 65536 + buf * 16384 + row * 64 +
                           (koff ^ (((row >> 1) & 3) << 4)));
  };

  // ---------- phase A: S = Q K^T ----------
  f32x4 acc[2][16] = {};
  stageT(Kh, 0, 0);
  stageT(Kh, 1, 1);
#pragma unroll
  for (int t = 0; t < 8; ++t) {
    if (t < 6)
      stageT(Kh, (t + 2) & 3, t + 2);
    else
      stageT(Vh, (t + 2) & 3, t - 6);  // global tiles 8,9 = V0,V1
    VMW(4);  // tile t fully in LDS; {t+1,t+2} (2 loads each) still in flight
    barrier_fenced();
#pragma unroll
    for (int j = 0; j < 16; ++j) {
      f16x8 b = ldfrag(t & 3, j * 16 + l15, lg * 16);
#pragma unroll
      for (int i = 0; i < 2; ++i)
        acc[i][j] =
            __builtin_amdgcn_mfma_f32_16x16x32_f16(qf[i][t], b, acc[i][j], 0, 0, 0);
    }
  }

  // ---------- softmax over 256 cols (rows wave-local) ----------
  // S[q=w32+i*16+lg*4+jj][n=j*16+l15] in acc[i][j][jj]; scale 1/16 in exp2 arg
  const float SCL = 0.0625f * 1.44269504089f;
  float inv[2][4];
#pragma unroll
  for (int i = 0; i < 2; ++i) {
#pragma unroll
    for (int jj = 0; jj < 4; ++jj) {
      float m_ = acc[i][0][jj];
#pragma unroll
      for (int f = 1; f < 16; ++f) m_ = fmaxf(m_, acc[i][f][jj]);
#pragma unroll
      for (int off = 1; off < 16; off <<= 1) m_ = fmaxf(m_, __shfl_xor(m_, off, 64));
      float s_ = 0.f;
#pragma unroll
      for (int f = 0; f < 16; ++f) {
        float e = __builtin_exp2f((acc[i][f][jj] - m_) * SCL);
        acc[i][f][jj] = e;
        s_ += e;
      }
#pragma unroll
      for (int off = 1; off < 16; off <<= 1) s_ += __shfl_xor(s_, off, 64);
      inv[i][jj] = 1.f / s_;
    }
  }

  // pack P into f16x2 registers (frees the f32 acc before oacc goes live)
  f16x2 pv[2][16][2];
#pragma unroll
  for (int i = 0; i < 2; ++i)
#pragma unroll
    for (int f = 0; f < 16; ++f)
#pragma unroll
      for (int p = 0; p < 2; ++p) {
        f16x2 t2 = {(f16)(acc[i][f][2 * p] * inv[i][2 * p]),
                    (f16)(acc[i][f][2 * p + 1] * inv[i][2 * p + 1])};
        pv[i][f][p] = t2;
      }

  // write one 128-col half of P into LDS (wave-private rows; swizzled)
  auto writeP = [&](int half) {
#pragma unroll
    for (int i = 0; i < 2; ++i)
#pragma unroll
      for (int f = half * 8; f < half * 8 + 8; ++f)
#pragma unroll
        for (int p = 0; p < 2; ++p)
#pragma unroll
          for (int q = 0; q < 2; ++q) {
            int row = w32 + i * 16 + lg * 4 + 2 * p + q;
            int colb = ((f & 7) * 16 + l15) * 2;
            *(f16*)(smem + row * 256 + (colb ^ ((row & 7) << 4))) = pv[i][f][p][q];
          }
  };
  writeP(0);

  // ---------- phase B: O = P V (B operand = V^T tiles) ----------
  f32x4 oacc[2][16] = {};
#pragma unroll
  for (int tv = 0; tv < 8; ++tv) {
    if (tv == 4) writeP(1);  // cols 128..255, used from tv=4 on (wave-private)
    if (tv < 6) stageT(Vh, (tv + 2) & 3, tv + 2);
    if (tv < 6) {
      VMW(4);
    } else if (tv == 6) {
      VMW(2);
    } else {
      VMW(0);
    }
    barrier_fenced();
    f16x8 pf[2];
#pragma unroll
    for (int i = 0; i < 2; ++i) {
      int row = w32 + i * 16 + l15;
      pf[i] = *(const f16x8*)(smem + row * 256 +
                              (((tv & 3) * 64 + lg * 16) ^ ((row & 7) << 4)));
    }
#pragma unroll
    for (int j = 0; j < 16; ++j) {
      f16x8 b = ldfrag(tv & 3, j * 16 + l15, lg * 16);
#pragma unroll
      for (int i = 0; i < 2; ++i)
        oacc[i][j] =
            __builtin_amdgcn_mfma_f32_16x16x32_f16(pf[i], b, oacc[i][j], 0, 0, 0);
    }
  }

  // write O tile into the Q slice (aliased; this block's Q reads are done)
#pragma unroll
  for (int i = 0; i < 2; ++i)
#pragma unroll
    for (int f = 0; f < 16; ++f)
#pragma unroll
      for (int jj = 0; jj < 4; ++jj) {
        int q = w32 + i * 16 + lg * 4 + jj;
        int d = f * 16 + l15;
        Ow[base + (long)q * 256 + d] = (f16)(oacc[i][f][jj]);
      }
}

// ---------------- launch ----------------
// ws layout (bytes):
//   xb    @ 0         8388608   fp16 x [16384][256]
//   WqT   @ 8388608   1048576   [2048][256] permuted-transposed   (contiguous
//   WkT   @ 9437184   1048576    with WqT -> fused QK B operand [4096][256])
//   WvT   @ 10485760  1048576
//   WoT   @ 11534336  1048576   [256][2048] permuted-transposed
//   bqp   @ 12582912  8192      (contiguous with bkp -> fused bias [4096])
//   bkp   @ 12591104  8192
//   bvp   @ 12599296  8192
//   QK    @ 12607488  134217728 interleaved [bc][qk][h][q][d] f16
//                               (attn O overwrites the qk=0 half in place)
//   VT    @ +134217728 67108864 [bc][h][d][q] f16
extern "C" void kernel_launch(void* const* d_in, const int* in_sizes, int n_in,
                              void* d_out, int out_size, void* d_ws,
                              size_t ws_size, hipStream_t stream) {
  const float* x = (const float*)d_in[0];
  const float* Wq = (const float*)d_in[1];
  const float* bq = (const float*)d_in[2];
  const float* Wk = (const float*)d_in[3];
  const float* bk = (const float*)d_in[4];
  const float* Wv = (const float*)d_in[5];
  const float* bv = (const float*)d_in[6];
  const float* Wo = (const float*)d_in[7];
  const float* bo = (const float*)d_in[8];

  char* ws = (char*)d_ws;
  f16* xb = (f16*)(ws + 0);
  f16* WqT = (f16*)(ws + 8388608);
  f16* WkT = (f16*)(ws + 9437184);
  f16* WvT = (f16*)(ws + 10485760);
  f16* WoT = (f16*)(ws + 11534336);
  float* bqp = (float*)(ws + 12582912);
  float* bkp = (float*)(ws + 12591104);
  float* bvp = (float*)(ws + 12599296);
  f16* QKws = (f16*)(ws + 12607488);
  f16* VTs = (f16*)(ws + 12607488 + 134217728L);
  if (ws_size < 12607488ull + 134217728ull + 67108864ull) return;  // ~204MB

  prep_x<<<4096, 256, 0, stream>>>(x, xb);
  prep_w<<<2048, 256, 0, stream>>>(Wq, Wk, Wv, Wo, bq, bk, bv, WqT, WkT, WvT,
                                   WoT, bqp, bkp, bvp);

  // fused Q+K projection: M=16384 tokens, N=4096 (qk*2048 + h*256 + d), K=256
  // C off = bc*1048576 + (m&255)*256 + (qk*8+h)*65536 + d
  gemm128<0><<<dim3(32, 128), 256, 0, stream>>>(xb, WqT, bqp, QKws, 256, 65536,
                                                0, 256, 1048576L, 65536L);
  // V projection, swapped operands -> V^T per head: M=2048 (n'), N=16384 tokens
  gemm128<1><<<dim3(128, 16), 256, 0, stream>>>(WvT, xb, bvp, VTs, 256, 65536,
                                                0, 256, 65536L, 524288L);

  attn_fused3<<<dim3(8, 64), 512, 0, stream>>>(QKws, VTs, QKws);

  // output projection: M=16384, N=256, K=2048 (head-blocked A), fp32 out + bo
  gemm128<2><<<dim3(2, 128), 256, 0, stream>>>(QKws, WoT, bo, d_out, 2048,
                                               1048576, 65536, 2048, 65536L, 0L);
}

// Round 4
// 245.696 us; speedup vs baseline: 1.2242x; 1.2242x over previous
//
#include <hip/hip_runtime.h>
#include <hip/hip_fp16.h>

typedef _Float16 f16;
typedef _Float16 f16x8 __attribute__((ext_vector_type(8)));
typedef _Float16 f16x4 __attribute__((ext_vector_type(4)));
typedef _Float16 f16x2 __attribute__((ext_vector_type(2)));
typedef float f32x4 __attribute__((ext_vector_type(4)));

#define GLB(p) ((const __attribute__((address_space(1))) void*)(p))
#define LDSP(p) ((__attribute__((address_space(3))) void*)(p))

__device__ __forceinline__ void gload16(const void* g, void* l) {
  __builtin_amdgcn_global_load_lds(GLB(g), LDSP(l), 16, 0, 0);
}

// counted vmcnt wait (immediate) + compiler-fenced barrier
#define VMW(n) asm volatile("s_waitcnt vmcnt(" #n ")" ::: "memory")
__device__ __forceinline__ void barrier_fenced() {
  asm volatile("" ::: "memory");
  __builtin_amdgcn_s_barrier();
  asm volatile("" ::: "memory");
}

// ---------------- prep ----------------
__global__ __launch_bounds__(256) void prep_x(const float* __restrict__ x,
                                              f16* __restrict__ xb) {
  int i = (blockIdx.x * 256 + threadIdx.x) * 4;
  float4 v = *(const float4*)(x + i);
  f16x4 o = {(f16)v.x, (f16)v.y, (f16)v.z, (f16)v.w};
  *(f16x4*)(xb + i) = o;
}

// WT'[n'][c] = W[c][(n'&255)*8 + (n'>>8)]   (n' = h*256+d, src n = d*8+h)
// WoT'[dm][n'] = Wo[(d*8+h)*256 + dm]
__global__ __launch_bounds__(256) void prep_w(
    const float* __restrict__ Wq, const float* __restrict__ Wk,
    const float* __restrict__ Wv, const float* __restrict__ Wo,
    const float* __restrict__ bq, const float* __restrict__ bk,
    const float* __restrict__ bv,
    f16* __restrict__ WqT, f16* __restrict__ WkT, f16* __restrict__ WvT,
    f16* __restrict__ WoT, float* __restrict__ bqp, float* __restrict__ bkp,
    float* __restrict__ bvp) {
  int i = blockIdx.x * 256 + threadIdx.x;  // 0..524287
  {
    int np = i >> 8, c = i & 255;
    int src = c * 2048 + (np & 255) * 8 + (np >> 8);
    WqT[i] = (f16)Wq[src];
    WkT[i] = (f16)Wk[src];
    WvT[i] = (f16)Wv[src];
  }
  {
    int dm = i >> 11, np = i & 2047;
    WoT[i] = (f16)Wo[((np & 255) * 8 + (np >> 8)) * 256 + dm];
  }
  if (i < 2048) {
    int src = (i & 255) * 8 + (i >> 8);
    bqp[i] = bq[src];
    bkp[i] = bk[src];
    bvp[i] = bv[src];
  }
}

// ---------------- generic 128x128 fp16 GEMM, K-innermost operands ----------------
// 4-buffer pipeline, counted vmcnt (prefetch distance 2, top barrier).
// A(m,k) elem = (m>>8)*aq1 + (m&255)*256 + (k>>8)*aq3 + (k&255)
// B(n,k) elem = n*ldb + k
// C(m,n) elem = (m>>8)*cp1 + (m&255)*256 + (n>>8)*cp3 + (n&255)
// OUTMODE: 0 = f16 out + col bias, 1 = f16 out + row bias, 2 = f32 out + col bias
template <int OUTMODE>
__global__ __launch_bounds__(256, 4) void gemm128(
    const f16* __restrict__ A, const f16* __restrict__ B,
    const float* __restrict__ bias, void* __restrict__ Cptr, int K, int aq1,
    int aq3, int ldb, long cp1, long cp3) {
  __shared__ f16 As[4][128 * 32];
  __shared__ f16 Bs[4][128 * 32];
  const int tid = threadIdx.x;
  const int m0 = blockIdx.y * 128;
  const int n0 = blockIdx.x * 128;
  const int lane = tid & 63, wid = tid >> 6;
  const int l15 = lane & 15, lg = lane >> 4;
  const int wm = (wid >> 1) * 64, wn = (wid & 1) * 64;

  f32x4 acc[4][4] = {};

  auto stage = [&](int buf, int kt) {
    int k0 = kt * 32;
#pragma unroll
    for (int r = 0; r < 2; ++r) {
      int flat = r * 4096 + tid * 16;  // byte offset within 8KB tile
      int row = flat >> 6;             // 64B per row
      int kk = k0 + ((flat & 63) >> 1);
      int m = m0 + row;
      gload16(A + (long)(m >> 8) * aq1 + (long)(m & 255) * 256 +
                  (long)(kk >> 8) * aq3 + (kk & 255),
              (char*)(&As[buf][0]) + flat);
      int n = n0 + row;
      gload16(B + (long)n * ldb + kk, (char*)(&Bs[buf][0]) + flat);
    }
  };

  auto compute = [&](int t) {
    const f16* as = &As[t & 3][0];
    const f16* bs = &Bs[t & 3][0];
    f16x8 af[4], bf[4];
#pragma unroll
    for (int i = 0; i < 4; ++i)
      af[i] = *(const f16x8*)(as + (wm + i * 16 + l15) * 32 + lg * 8);
#pragma unroll
    for (int j = 0; j < 4; ++j)
      bf[j] = *(const f16x8*)(bs + (wn + j * 16 + l15) * 32 + lg * 8);
#pragma unroll
    for (int i = 0; i < 4; ++i)
#pragma unroll
      for (int j = 0; j < 4; ++j)
        acc[i][j] =
            __builtin_amdgcn_mfma_f32_16x16x32_f16(af[i], bf[j], acc[i][j], 0, 0, 0);
  };

  const int T = K >> 5;  // always >= 8
  stage(0, 0);
  stage(1, 1);
  for (int t = 0; t < T - 2; ++t) {
    stage((t + 2) & 3, t + 2);
    VMW(8);   // tiles {t+1, t+2} (4 loads each) may remain in flight
    barrier_fenced();
    compute(t);
  }
  VMW(4);  // only tile T-1 in flight
  barrier_fenced();
  compute(T - 2);
  VMW(0);
  barrier_fenced();
  compute(T - 1);

#pragma unroll
  for (int i = 0; i < 4; ++i) {
#pragma unroll
    for (int j = 0; j < 4; ++j) {
#pragma unroll
      for (int jj = 0; jj < 4; ++jj) {
        int m = m0 + wm + i * 16 + lg * 4 + jj;
        int n = n0 + wn + j * 16 + l15;
        float v = acc[i][j][jj];
        v += (OUTMODE == 1) ? bias[m] : bias[n];
        long off = (long)(m >> 8) * cp1 + (long)(m & 255) * 256 +
                   (long)(n >> 8) * cp3 + (n & 255);
        if (OUTMODE == 2)
          ((float*)Cptr)[off] = v;
        else
          ((f16*)Cptr)[off] = (f16)v;
      }
    }
  }
}

// ---------------- fused attention v4: one block per (bc,h), q-tile = 256 ----------------
// 512 threads = 8 waves; wave w owns q rows [w*32, w*32+32).
// Round-2 register profile (acc -> P in LDS -> oacc; no long-lived Q/P register
// arrays => no spills) + non-draining counted-vmcnt pipeline:
//   phase A: Q tiles qb[4], K tiles kb[4] (16KB each, 8*16KB = 128KB = P region),
//            prefetch distance 2, VMW(8) -- loads stay in flight across barriers.
//   phase B: V^T as 16 sub-tiles [128 d][32 k] (8KB) through 4 bufs @131072,
//            distance 2, VMW(2). V0/V1 issued in phase A tail (hide under softmax).
// LDS = 160KB exactly. P rows are wave-private: no barriers around P write/read.
__global__ __launch_bounds__(512, 2) void attn_fused4(const f16* __restrict__ QK,
                                                      const f16* __restrict__ Vw,
                                                      f16* __restrict__ Ow) {
  __shared__ __align__(16) char smem[163840];
  const int tid = threadIdx.x;
  const int lane = tid & 63, wid = tid >> 6;
  const int l15 = lane & 15, lg = lane >> 4;
  const int h = blockIdx.x, bc = blockIdx.y;
  const long base = (long)bc * 1048576 + (long)h * 65536;  // Q slice in interleaved QK
  const f16* Qh = QK + base;
  const f16* Kh = QK + base + 524288;
  const f16* Vh = Vw + (long)bc * 524288 + (long)h * 65536;  // V^T [d][q]
  const int w32 = wid * 32;

  // stage Q(t)+K(t) [256 rows][32 k] tiles; source-side swizzle so physical
  // byte = row*64 + (colbytes ^ (((row>>1)&3)<<4)); LDS dest linear.
  auto stagePair = [&](int t) {
    int buf = t & 3;
#pragma unroll
    for (int r = 0; r < 2; ++r) {
      int flat = r * 8192 + tid * 16;
      int row = flat >> 6;
      int kk = t * 32 + (((flat ^ (((row >> 1) & 3) << 4)) & 63) >> 1);
      gload16(Qh + (long)row * 256 + kk, smem + buf * 16384 + flat);
      gload16(Kh + (long)row * 256 + kk, smem + 65536 + buf * 16384 + flat);
    }
  };
  // V sub-tile st: d-half (st&1)*128, k-cols (st>>1)*32; [128][32] = 8KB, 1 load/thread
  auto stageV = [&](int st) {
    int flat = tid * 16;
    int row = flat >> 6;  // 0..127
    int kk = (st >> 1) * 32 + (((flat ^ (((row >> 1) & 3) << 4)) & 63) >> 1);
    gload16(Vh + (long)((st & 1) * 128 + row) * 256 + kk,
            smem + 131072 + (st & 3) * 8192 + flat);
  };
  auto ldQ = [&](int t, int row, int koff) -> f16x8 {
    return *(const f16x8*)(smem + (t & 3) * 16384 + row * 64 +
                           (koff ^ (((row >> 1) & 3) << 4)));
  };
  auto ldK = [&](int t, int row, int koff) -> f16x8 {
    return *(const f16x8*)(smem + 65536 + (t & 3) * 16384 + row * 64 +
                           (koff ^ (((row >> 1) & 3) << 4)));
  };
  auto ldV = [&](int st, int row, int koff) -> f16x8 {
    return *(const f16x8*)(smem + 131072 + (st & 3) * 8192 + row * 64 +
                           (koff ^ (((row >> 1) & 3) << 4)));
  };

  // ---------- phase A: S = Q K^T ----------
  f32x4 acc[2][16] = {};
  stagePair(0);
  stagePair(1);
#pragma unroll
  for (int t = 0; t < 8; ++t) {
    if (t < 6) {
      stagePair(t + 2);
      VMW(8);  // pairs {t+1,t+2} (4 loads each) stay in flight
    } else if (t == 6) {
      stageV(0);
      stageV(1);
      VMW(6);  // pair 7 (4) + V0,V1 (2) in flight
    } else {
      VMW(2);  // V0,V1 in flight through softmax
    }
    barrier_fenced();
    f16x8 af[2];
#pragma unroll
    for (int i = 0; i < 2; ++i) af[i] = ldQ(t, w32 + i * 16 + l15, lg * 16);
    __builtin_amdgcn_s_setprio(1);
#pragma unroll
    for (int j = 0; j < 16; ++j) {
      f16x8 b = ldK(t, j * 16 + l15, lg * 16);
#pragma unroll
      for (int i = 0; i < 2; ++i)
        acc[i][j] =
            __builtin_amdgcn_mfma_f32_16x16x32_f16(af[i], b, acc[i][j], 0, 0, 0);
    }
    __builtin_amdgcn_s_setprio(0);
  }
  barrier_fenced();  // all waves' Q/K LDS reads done; P may overwrite region

  // ---------- softmax over 256 cols (rows wave-local) ----------
  // S[q=w32+i*16+lg*4+jj][n=j*16+l15] in acc[i][j][jj]; scale 1/16 in exp2 arg
  const float SCL = 0.0625f * 1.44269504089f;
  float inv[2][4];
#pragma unroll
  for (int i = 0; i < 2; ++i) {
#pragma unroll
    for (int jj = 0; jj < 4; ++jj) {
      float m_ = acc[i][0][jj];
#pragma unroll
      for (int f = 1; f < 16; ++f) m_ = fmaxf(m_, acc[i][f][jj]);
#pragma unroll
      for (int off = 1; off < 16; off <<= 1) m_ = fmaxf(m_, __shfl_xor(m_, off, 64));
      float s_ = 0.f;
#pragma unroll
      for (int f = 0; f < 16; ++f) {
        float e = __builtin_exp2f((acc[i][f][jj] - m_) * SCL);
        acc[i][f][jj] = e;
        s_ += e;
      }
#pragma unroll
      for (int off = 1; off < 16; off <<= 1) s_ += __shfl_xor(s_, off, 64);
      inv[i][jj] = 1.f / s_;
    }
  }

  // write P [256 rows][256 cols] f16 @smem[0..131072), swizzled:
  // byte = row*512 + (col*2 ^ ((row&7)<<4)); rows wave-private
#pragma unroll
  for (int i = 0; i < 2; ++i)
#pragma unroll
    for (int f = 0; f < 16; ++f)
#pragma unroll
      for (int jj = 0; jj < 4; ++jj) {
        int row = w32 + i * 16 + lg * 4 + jj;
        int colb = (f * 16 + l15) * 2;
        *(f16*)(smem + row * 512 + (colb ^ ((row & 7) << 4))) =
            (f16)(acc[i][f][jj] * inv[i][jj]);
      }

  // ---------- phase B: O = P V over 16 V sub-tiles ----------
  f32x4 oacc[2][16] = {};
#pragma unroll
  for (int st = 0; st < 16; ++st) {
    if (st < 14) {
      stageV(st + 2);
      VMW(2);  // sub-tiles {st+1,st+2} in flight
    } else if (st == 14) {
      VMW(1);
    } else {
      VMW(0);
    }
    barrier_fenced();
    const int t = st >> 1, dh = st & 1;
    f16x8 pf[2];
#pragma unroll
    for (int i = 0; i < 2; ++i) {
      int row = w32 + i * 16 + l15;
      pf[i] = *(const f16x8*)(smem + row * 512 +
                              ((t * 64 + lg * 16) ^ ((row & 7) << 4)));
    }
    __builtin_amdgcn_s_setprio(1);
#pragma unroll
    for (int jj = 0; jj < 8; ++jj) {
      f16x8 b = ldV(st, jj * 16 + l15, lg * 16);
      const int j = dh * 8 + jj;
#pragma unroll
      for (int i = 0; i < 2; ++i)
        oacc[i][j] =
            __builtin_amdgcn_mfma_f32_16x16x32_f16(pf[i], b, oacc[i][j], 0, 0, 0);
    }
    __builtin_amdgcn_s_setprio(0);
  }

  // write O tile into the Q slice (aliased; this block's Q reads are done)
#pragma unroll
  for (int i = 0; i < 2; ++i)
#pragma unroll
    for (int f = 0; f < 16; ++f)
#pragma unroll
      for (int jj = 0; jj < 4; ++jj) {
        int q = w32 + i * 16 + lg * 4 + jj;
        int d = f * 16 + l15;
        Ow[base + (long)q * 256 + d] = (f16)(oacc[i][f][jj]);
      }
}

// ---------------- launch ----------------
// ws layout (bytes):
//   xb    @ 0         8388608   fp16 x [16384][256]
//   WqT   @ 8388608   1048576   [2048][256] permuted-transposed   (contiguous
//   WkT   @ 9437184   1048576    with WqT -> fused QK B operand [4096][256])
//   WvT   @ 10485760  1048576
//   WoT   @ 11534336  1048576   [256][2048] permuted-transposed
//   bqp   @ 12582912  8192      (contiguous with bkp -> fused bias [4096])
//   bkp   @ 12591104  8192
//   bvp   @ 12599296  8192
//   QK    @ 12607488  134217728 interleaved [bc][qk][h][q][d] f16
//                               (attn O overwrites the qk=0 half in place)
//   VT    @ +134217728 67108864 [bc][h][d][q] f16
extern "C" void kernel_launch(void* const* d_in, const int* in_sizes, int n_in,
                              void* d_out, int out_size, void* d_ws,
                              size_t ws_size, hipStream_t stream) {
  const float* x = (const float*)d_in[0];
  const float* Wq = (const float*)d_in[1];
  const float* bq = (const float*)d_in[2];
  const float* Wk = (const float*)d_in[3];
  const float* bk = (const float*)d_in[4];
  const float* Wv = (const float*)d_in[5];
  const float* bv = (const float*)d_in[6];
  const float* Wo = (const float*)d_in[7];
  const float* bo = (const float*)d_in[8];

  char* ws = (char*)d_ws;
  f16* xb = (f16*)(ws + 0);
  f16* WqT = (f16*)(ws + 8388608);
  f16* WkT = (f16*)(ws + 9437184);
  f16* WvT = (f16*)(ws + 10485760);
  f16* WoT = (f16*)(ws + 11534336);
  float* bqp = (float*)(ws + 12582912);
  float* bkp = (float*)(ws + 12591104);
  float* bvp = (float*)(ws + 12599296);
  f16* QKws = (f16*)(ws + 12607488);
  f16* VTs = (f16*)(ws + 12607488 + 134217728L);
  if (ws_size < 12607488ull + 134217728ull + 67108864ull) return;  // ~204MB

  prep_x<<<4096, 256, 0, stream>>>(x, xb);
  prep_w<<<2048, 256, 0, stream>>>(Wq, Wk, Wv, Wo, bq, bk, bv, WqT, WkT, WvT,
                                   WoT, bqp, bkp, bvp);

  // fused Q+K projection: M=16384 tokens, N=4096 (qk*2048 + h*256 + d), K=256
  // C off = bc*1048576 + (m&255)*256 + (qk*8+h)*65536 + d
  gemm128<0><<<dim3(32, 128), 256, 0, stream>>>(xb, WqT, bqp, QKws, 256, 65536,
                                                0, 256, 1048576L, 65536L);
  // V projection, swapped operands -> V^T per head: M=2048 (n'), N=16384 tokens
  gemm128<1><<<dim3(128, 16), 256, 0, stream>>>(WvT, xb, bvp, VTs, 256, 65536,
                                                0, 256, 65536L, 524288L);

  attn_fused4<<<dim3(8, 64), 512, 0, stream>>>(QKws, VTs, QKws);

  // output projection: M=16384, N=256, K=2048 (head-blocked A), fp32 out + bo
  gemm128<2><<<dim3(2, 128), 256, 0, stream>>>(QKws, WoT, bo, d_out, 2048,
                                               1048576, 65536, 2048, 65536L, 0L);
}

// Round 5
// 236.717 us; speedup vs baseline: 1.2706x; 1.0379x over previous
//
#include <hip/hip_runtime.h>
#include <hip/hip_fp16.h>

typedef _Float16 f16;
typedef _Float16 f16x8 __attribute__((ext_vector_type(8)));
typedef _Float16 f16x4 __attribute__((ext_vector_type(4)));
typedef _Float16 f16x2 __attribute__((ext_vector_type(2)));
typedef float f32x4 __attribute__((ext_vector_type(4)));
typedef float f32x16 __attribute__((ext_vector_type(16)));

#define GLB(p) ((const __attribute__((address_space(1))) void*)(p))
#define LDSP(p) ((__attribute__((address_space(3))) void*)(p))

__device__ __forceinline__ void gload16(const void* g, void* l) {
  __builtin_amdgcn_global_load_lds(GLB(g), LDSP(l), 16, 0, 0);
}

// counted vmcnt wait (immediate) + compiler-fenced barrier
#define VMW(n) asm volatile("s_waitcnt vmcnt(" #n ")" ::: "memory")
__device__ __forceinline__ void barrier_fenced() {
  asm volatile("" ::: "memory");
  __builtin_amdgcn_s_barrier();
  asm volatile("" ::: "memory");
}

// ---------------- prep ----------------
__global__ __launch_bounds__(256) void prep_x(const float* __restrict__ x,
                                              f16* __restrict__ xb) {
  int i = (blockIdx.x * 256 + threadIdx.x) * 4;
  float4 v = *(const float4*)(x + i);
  f16x4 o = {(f16)v.x, (f16)v.y, (f16)v.z, (f16)v.w};
  *(f16x4*)(xb + i) = o;
}

// WT'[n'][c] = W[c][(n'&255)*8 + (n'>>8)]   (n' = h*256+d, src n = d*8+h)
// WoT'[dm][n'] = Wo[(d*8+h)*256 + dm]
__global__ __launch_bounds__(256) void prep_w(
    const float* __restrict__ Wq, const float* __restrict__ Wk,
    const float* __restrict__ Wv, const float* __restrict__ Wo,
    const float* __restrict__ bq, const float* __restrict__ bk,
    const float* __restrict__ bv,
    f16* __restrict__ WqT, f16* __restrict__ WkT, f16* __restrict__ WvT,
    f16* __restrict__ WoT, float* __restrict__ bqp, float* __restrict__ bkp,
    float* __restrict__ bvp) {
  int i = blockIdx.x * 256 + threadIdx.x;  // 0..524287
  {
    int np = i >> 8, c = i & 255;
    int src = c * 2048 + (np & 255) * 8 + (np >> 8);
    WqT[i] = (f16)Wq[src];
    WkT[i] = (f16)Wk[src];
    WvT[i] = (f16)Wv[src];
  }
  {
    int dm = i >> 11, np = i & 2047;
    WoT[i] = (f16)Wo[((np & 255) * 8 + (np >> 8)) * 256 + dm];
  }
  if (i < 2048) {
    int src = (i & 255) * 8 + (i >> 8);
    bqp[i] = bq[src];
    bkp[i] = bk[src];
    bvp[i] = bv[src];
  }
}

// ---------------- 256x256-tile fp16 GEMM, 32x32x16 MFMA, K=256 fixed ----------------
// A(m,k) elem = (m>>8)*aq1 + (m&255)*256 + k      (K-innermost)
// B(n,k) elem = n*256 + k
// C(m,n) elem = (m>>8)*cp1 + (m&255)*256 + (n>>8)*cp3 + (n&255)   (f16)
// OUTMODE: 0 = col bias (bias[n]), 1 = row bias (bias[m])
// 512 threads = 8 waves (2 rows x 4 cols); per-wave output 128x64.
// 3 rotating buffer-sets (A 16KB + B 16KB each), prefetch distance 2,
// one vmcnt(4)+barrier per K-tile; stages interleaved between k-phases.
template <int OUTMODE>
__global__ __launch_bounds__(512, 2) void gemm256(
    const f16* __restrict__ A, const f16* __restrict__ B,
    const float* __restrict__ bias, f16* __restrict__ C, int NT, int aq1,
    long cp1, long cp3) {
  __shared__ __align__(16) char smem[98304];
  const int tid = threadIdx.x;
  const int lane = tid & 63;
  const int wid = tid >> 6;
  const int l31 = lane & 31, lh = lane >> 5;  // lh selects k-half of a fragment
  const int wr = wid >> 2, wc = wid & 3;      // wave grid 2(M) x 4(N)
  // XCD-bijective swizzle (grid size is a multiple of 8)
  const int nwg = gridDim.x, bid = blockIdx.x;
  const int sw = (bid & 7) * (nwg >> 3) + (bid >> 3);
  const int n0 = (sw % NT) * 256, m0 = (sw / NT) * 256;

  // stage [256 rows][32 k] f16 tiles; source-side swizzle so physical
  // byte = row*64 + (colbytes ^ (((row>>1)&3)<<4)); LDS dest linear.
  auto stageA = [&](int buf, int kt) {
#pragma unroll
    for (int r = 0; r < 2; ++r) {
      int flat = r * 8192 + tid * 16;
      int row = flat >> 6;
      int kk = kt * 32 + (((flat ^ (((row >> 1) & 3) << 4)) & 63) >> 1);
      int m = m0 + row;
      gload16(A + (long)(m >> 8) * aq1 + (long)(m & 255) * 256 + kk,
              smem + buf * 16384 + flat);
    }
  };
  auto stageB = [&](int buf, int kt) {
#pragma unroll
    for (int r = 0; r < 2; ++r) {
      int flat = r * 8192 + tid * 16;
      int row = flat >> 6;
      int kk = kt * 32 + (((flat ^ (((row >> 1) & 3) << 4)) & 63) >> 1);
      gload16(B + (long)(n0 + row) * 256 + kk,
              smem + 49152 + buf * 16384 + flat);
    }
  };
  // fragment reads for 32x32x16: lane holds row (lane&31), k = lh*8 + j
  auto ldA = [&](int buf, int row, int kf) -> f16x8 {
    int cb = kf * 32 + lh * 16;
    return *(const f16x8*)(smem + buf * 16384 + row * 64 +
                           (cb ^ (((row >> 1) & 3) << 4)));
  };
  auto ldB = [&](int buf, int row, int kf) -> f16x8 {
    int cb = kf * 32 + lh * 16;
    return *(const f16x8*)(smem + 49152 + buf * 16384 + row * 64 +
                           (cb ^ (((row >> 1) & 3) << 4)));
  };

  f32x16 acc[4][2] = {};
  stageA(0, 0);
  stageB(0, 0);
  stageA(1, 1);
  stageB(1, 1);
#pragma unroll
  for (int t = 0; t < 8; ++t) {
    if (t < 7) {
      VMW(4);  // tile t landed; tile t+1 (4 loads) stays in flight
    } else {
      VMW(0);
    }
    barrier_fenced();  // all waves' tile-t loads visible; buf (t+2)%3 free
    const int buf = t % 3;
    const int sb = (t + 2) % 3;
    // ---- k-phase 0 ----
    f16x8 a[4], b[2];
#pragma unroll
    for (int mi = 0; mi < 4; ++mi) a[mi] = ldA(buf, wr * 128 + mi * 32 + l31, 0);
#pragma unroll
    for (int ni = 0; ni < 2; ++ni) b[ni] = ldB(buf, wc * 64 + ni * 32 + l31, 0);
    if (t < 6) stageA(sb, t + 2);
    __builtin_amdgcn_s_setprio(1);
#pragma unroll
    for (int mi = 0; mi < 4; ++mi)
#pragma unroll
      for (int ni = 0; ni < 2; ++ni)
        acc[mi][ni] = __builtin_amdgcn_mfma_f32_32x32x16_f16(a[mi], b[ni],
                                                             acc[mi][ni], 0, 0, 0);
    __builtin_amdgcn_s_setprio(0);
    // ---- k-phase 1 ----
#pragma unroll
    for (int mi = 0; mi < 4; ++mi) a[mi] = ldA(buf, wr * 128 + mi * 32 + l31, 1);
#pragma unroll
    for (int ni = 0; ni < 2; ++ni) b[ni] = ldB(buf, wc * 64 + ni * 32 + l31, 1);
    if (t < 6) stageB(sb, t + 2);
    __builtin_amdgcn_s_setprio(1);
#pragma unroll
    for (int mi = 0; mi < 4; ++mi)
#pragma unroll
      for (int ni = 0; ni < 2; ++ni)
        acc[mi][ni] = __builtin_amdgcn_mfma_f32_32x32x16_f16(a[mi], b[ni],
                                                             acc[mi][ni], 0, 0, 0);
    __builtin_amdgcn_s_setprio(0);
  }

  // epilogue: C/D layout col=lane&31, row=(reg&3)+8*(reg>>2)+4*(lane>>5)
#pragma unroll
  for (int mi = 0; mi < 4; ++mi)
#pragma unroll
    for (int ni = 0; ni < 2; ++ni)
#pragma unroll
      for (int reg = 0; reg < 16; ++reg) {
        int m = m0 + wr * 128 + mi * 32 + (reg & 3) + 8 * (reg >> 2) + 4 * lh;
        int n = n0 + wc * 64 + ni * 32 + l31;
        float v = acc[mi][ni][reg];
        v += (OUTMODE == 1) ? bias[m] : bias[n];
        long off = (long)(m >> 8) * cp1 + (long)(m & 255) * 256 +
                   (long)(n >> 8) * cp3 + (n & 255);
        C[off] = (f16)v;
      }
}

// ---------------- generic 128x128 fp16 GEMM (kept for O-proj, K=2048) ----------------
// A(m,k) elem = (m>>8)*aq1 + (m&255)*256 + (k>>8)*aq3 + (k&255)
// B(n,k) elem = n*ldb + k
// C(m,n) elem = (m>>8)*cp1 + (m&255)*256 + (n>>8)*cp3 + (n&255)
// OUTMODE: 0 = f16 out + col bias, 1 = f16 out + row bias, 2 = f32 out + col bias
template <int OUTMODE>
__global__ __launch_bounds__(256, 4) void gemm128(
    const f16* __restrict__ A, const f16* __restrict__ B,
    const float* __restrict__ bias, void* __restrict__ Cptr, int K, int aq1,
    int aq3, int ldb, long cp1, long cp3) {
  __shared__ f16 As[4][128 * 32];
  __shared__ f16 Bs[4][128 * 32];
  const int tid = threadIdx.x;
  const int m0 = blockIdx.y * 128;
  const int n0 = blockIdx.x * 128;
  const int lane = tid & 63, wid = tid >> 6;
  const int l15 = lane & 15, lg = lane >> 4;
  const int wm = (wid >> 1) * 64, wn = (wid & 1) * 64;

  f32x4 acc[4][4] = {};

  auto stage = [&](int buf, int kt) {
    int k0 = kt * 32;
#pragma unroll
    for (int r = 0; r < 2; ++r) {
      int flat = r * 4096 + tid * 16;  // byte offset within 8KB tile
      int row = flat >> 6;             // 64B per row
      int kk = k0 + ((flat & 63) >> 1);
      int m = m0 + row;
      gload16(A + (long)(m >> 8) * aq1 + (long)(m & 255) * 256 +
                  (long)(kk >> 8) * aq3 + (kk & 255),
              (char*)(&As[buf][0]) + flat);
      int n = n0 + row;
      gload16(B + (long)n * ldb + kk, (char*)(&Bs[buf][0]) + flat);
    }
  };

  auto compute = [&](int t) {
    const f16* as = &As[t & 3][0];
    const f16* bs = &Bs[t & 3][0];
    f16x8 af[4], bf[4];
#pragma unroll
    for (int i = 0; i < 4; ++i)
      af[i] = *(const f16x8*)(as + (wm + i * 16 + l15) * 32 + lg * 8);
#pragma unroll
    for (int j = 0; j < 4; ++j)
      bf[j] = *(const f16x8*)(bs + (wn + j * 16 + l15) * 32 + lg * 8);
#pragma unroll
    for (int i = 0; i < 4; ++i)
#pragma unroll
      for (int j = 0; j < 4; ++j)
        acc[i][j] =
            __builtin_amdgcn_mfma_f32_16x16x32_f16(af[i], bf[j], acc[i][j], 0, 0, 0);
  };

  const int T = K >> 5;  // always >= 8
  stage(0, 0);
  stage(1, 1);
  for (int t = 0; t < T - 2; ++t) {
    stage((t + 2) & 3, t + 2);
    VMW(8);   // tiles {t+1, t+2} (4 loads each) may remain in flight
    barrier_fenced();
    compute(t);
  }
  VMW(4);  // only tile T-1 in flight
  barrier_fenced();
  compute(T - 2);
  VMW(0);
  barrier_fenced();
  compute(T - 1);

#pragma unroll
  for (int i = 0; i < 4; ++i) {
#pragma unroll
    for (int j = 0; j < 4; ++j) {
#pragma unroll
      for (int jj = 0; jj < 4; ++jj) {
        int m = m0 + wm + i * 16 + lg * 4 + jj;
        int n = n0 + wn + j * 16 + l15;
        float v = acc[i][j][jj];
        v += (OUTMODE == 1) ? bias[m] : bias[n];
        long off = (long)(m >> 8) * cp1 + (long)(m & 255) * 256 +
                   (long)(n >> 8) * cp3 + (n & 255);
        if (OUTMODE == 2)
          ((float*)Cptr)[off] = v;
        else
          ((f16*)Cptr)[off] = (f16)v;
      }
    }
  }
}

// ---------------- fused attention v4 (unchanged from round 4) ----------------
__global__ __launch_bounds__(512, 2) void attn_fused4(const f16* __restrict__ QK,
                                                      const f16* __restrict__ Vw,
                                                      f16* __restrict__ Ow) {
  __shared__ __align__(16) char smem[163840];
  const int tid = threadIdx.x;
  const int lane = tid & 63, wid = tid >> 6;
  const int l15 = lane & 15, lg = lane >> 4;
  const int h = blockIdx.x, bc = blockIdx.y;
  const long base = (long)bc * 1048576 + (long)h * 65536;  // Q slice in interleaved QK
  const f16* Qh = QK + base;
  const f16* Kh = QK + base + 524288;
  const f16* Vh = Vw + (long)bc * 524288 + (long)h * 65536;  // V^T [d][q]
  const int w32 = wid * 32;

  auto stagePair = [&](int t) {
    int buf = t & 3;
#pragma unroll
    for (int r = 0; r < 2; ++r) {
      int flat = r * 8192 + tid * 16;
      int row = flat >> 6;
      int kk = t * 32 + (((flat ^ (((row >> 1) & 3) << 4)) & 63) >> 1);
      gload16(Qh + (long)row * 256 + kk, smem + buf * 16384 + flat);
      gload16(Kh + (long)row * 256 + kk, smem + 65536 + buf * 16384 + flat);
    }
  };
  auto stageV = [&](int st) {
    int flat = tid * 16;
    int row = flat >> 6;  // 0..127
    int kk = (st >> 1) * 32 + (((flat ^ (((row >> 1) & 3) << 4)) & 63) >> 1);
    gload16(Vh + (long)((st & 1) * 128 + row) * 256 + kk,
            smem + 131072 + (st & 3) * 8192 + flat);
  };
  auto ldQ = [&](int t, int row, int koff) -> f16x8 {
    return *(const f16x8*)(smem + (t & 3) * 16384 + row * 64 +
                           (koff ^ (((row >> 1) & 3) << 4)));
  };
  auto ldK = [&](int t, int row, int koff) -> f16x8 {
    return *(const f16x8*)(smem + 65536 + (t & 3) * 16384 + row * 64 +
                           (koff ^ (((row >> 1) & 3) << 4)));
  };
  auto ldV = [&](int st, int row, int koff) -> f16x8 {
    return *(const f16x8*)(smem + 131072 + (st & 3) * 8192 + row * 64 +
                           (koff ^ (((row >> 1) & 3) << 4)));
  };

  // ---------- phase A: S = Q K^T ----------
  f32x4 acc[2][16] = {};
  stagePair(0);
  stagePair(1);
#pragma unroll
  for (int t = 0; t < 8; ++t) {
    if (t < 6) {
      stagePair(t + 2);
      VMW(8);
    } else if (t == 6) {
      stageV(0);
      stageV(1);
      VMW(6);
    } else {
      VMW(2);
    }
    barrier_fenced();
    f16x8 af[2];
#pragma unroll
    for (int i = 0; i < 2; ++i) af[i] = ldQ(t, w32 + i * 16 + l15, lg * 16);
    __builtin_amdgcn_s_setprio(1);
#pragma unroll
    for (int j = 0; j < 16; ++j) {
      f16x8 b = ldK(t, j * 16 + l15, lg * 16);
#pragma unroll
      for (int i = 0; i < 2; ++i)
        acc[i][j] =
            __builtin_amdgcn_mfma_f32_16x16x32_f16(af[i], b, acc[i][j], 0, 0, 0);
    }
    __builtin_amdgcn_s_setprio(0);
  }
  barrier_fenced();  // all waves' Q/K LDS reads done; P may overwrite region

  // ---------- softmax over 256 cols (rows wave-local) ----------
  const float SCL = 0.0625f * 1.44269504089f;
  float inv[2][4];
#pragma unroll
  for (int i = 0; i < 2; ++i) {
#pragma unroll
    for (int jj = 0; jj < 4; ++jj) {
      float m_ = acc[i][0][jj];
#pragma unroll
      for (int f = 1; f < 16; ++f) m_ = fmaxf(m_, acc[i][f][jj]);
#pragma unroll
      for (int off = 1; off < 16; off <<= 1) m_ = fmaxf(m_, __shfl_xor(m_, off, 64));
      float s_ = 0.f;
#pragma unroll
      for (int f = 0; f < 16; ++f) {
        float e = __builtin_exp2f((acc[i][f][jj] - m_) * SCL);
        acc[i][f][jj] = e;
        s_ += e;
      }
#pragma unroll
      for (int off = 1; off < 16; off <<= 1) s_ += __shfl_xor(s_, off, 64);
      inv[i][jj] = 1.f / s_;
    }
  }

  // write P [256 rows][256 cols] f16 @smem[0..131072), swizzled
#pragma unroll
  for (int i = 0; i < 2; ++i)
#pragma unroll
    for (int f = 0; f < 16; ++f)
#pragma unroll
      for (int jj = 0; jj < 4; ++jj) {
        int row = w32 + i * 16 + lg * 4 + jj;
        int colb = (f * 16 + l15) * 2;
        *(f16*)(smem + row * 512 + (colb ^ ((row & 7) << 4))) =
            (f16)(acc[i][f][jj] * inv[i][jj]);
      }

  // ---------- phase B: O = P V over 16 V sub-tiles ----------
  f32x4 oacc[2][16] = {};
#pragma unroll
  for (int st = 0; st < 16; ++st) {
    if (st < 14) {
      stageV(st + 2);
      VMW(2);
    } else if (st == 14) {
      VMW(1);
    } else {
      VMW(0);
    }
    barrier_fenced();
    const int t = st >> 1, dh = st & 1;
    f16x8 pf[2];
#pragma unroll
    for (int i = 0; i < 2; ++i) {
      int row = w32 + i * 16 + l15;
      pf[i] = *(const f16x8*)(smem + row * 512 +
                              ((t * 64 + lg * 16) ^ ((row & 7) << 4)));
    }
    __builtin_amdgcn_s_setprio(1);
#pragma unroll
    for (int jj = 0; jj < 8; ++jj) {
      f16x8 b = ldV(st, jj * 16 + l15, lg * 16);
      const int j = dh * 8 + jj;
#pragma unroll
      for (int i = 0; i < 2; ++i)
        oacc[i][j] =
            __builtin_amdgcn_mfma_f32_16x16x32_f16(pf[i], b, oacc[i][j], 0, 0, 0);
    }
    __builtin_amdgcn_s_setprio(0);
  }

  // write O tile into the Q slice (aliased; this block's Q reads are done)
#pragma unroll
  for (int i = 0; i < 2; ++i)
#pragma unroll
    for (int f = 0; f < 16; ++f)
#pragma unroll
      for (int jj = 0; jj < 4; ++jj) {
        int q = w32 + i * 16 + lg * 4 + jj;
        int d = f * 16 + l15;
        Ow[base + (long)q * 256 + d] = (f16)(oacc[i][f][jj]);
      }
}

// ---------------- launch ----------------
// ws layout (bytes):
//   xb    @ 0         8388608   fp16 x [16384][256]
//   WqT   @ 8388608   1048576   [2048][256] permuted-transposed   (contiguous
//   WkT   @ 9437184   1048576    with WqT -> fused QK B operand [4096][256])
//   WvT   @ 10485760  1048576
//   WoT   @ 11534336  1048576   [256][2048] permuted-transposed
//   bqp   @ 12582912  8192      (contiguous with bkp -> fused bias [4096])
//   bkp   @ 12591104  8192
//   bvp   @ 12599296  8192
//   QK    @ 12607488  134217728 interleaved [bc][qk][h][q][d] f16
//                               (attn O overwrites the qk=0 half in place)
//   VT    @ +134217728 67108864 [bc][h][d][q] f16
extern "C" void kernel_launch(void* const* d_in, const int* in_sizes, int n_in,
                              void* d_out, int out_size, void* d_ws,
                              size_t ws_size, hipStream_t stream) {
  const float* x = (const float*)d_in[0];
  const float* Wq = (const float*)d_in[1];
  const float* bq = (const float*)d_in[2];
  const float* Wk = (const float*)d_in[3];
  const float* bk = (const float*)d_in[4];
  const float* Wv = (const float*)d_in[5];
  const float* bv = (const float*)d_in[6];
  const float* Wo = (const float*)d_in[7];
  const float* bo = (const float*)d_in[8];

  char* ws = (char*)d_ws;
  f16* xb = (f16*)(ws + 0);
  f16* WqT = (f16*)(ws + 8388608);
  f16* WkT = (f16*)(ws + 9437184);
  f16* WvT = (f16*)(ws + 10485760);
  f16* WoT = (f16*)(ws + 11534336);
  float* bqp = (float*)(ws + 12582912);
  float* bkp = (float*)(ws + 12591104);
  float* bvp = (float*)(ws + 12599296);
  f16* QKws = (f16*)(ws + 12607488);
  f16* VTs = (f16*)(ws + 12607488 + 134217728L);
  if (ws_size < 12607488ull + 134217728ull + 67108864ull) return;  // ~204MB

  prep_x<<<4096, 256, 0, stream>>>(x, xb);
  prep_w<<<2048, 256, 0, stream>>>(Wq, Wk, Wv, Wo, bq, bk, bv, WqT, WkT, WvT,
                                   WoT, bqp, bkp, bvp);

  // fused Q+K projection: M=16384 tokens, N=4096 (qk*2048 + h*256 + d), K=256
  // grid 64 m-tiles x 16 n-tiles = 1024 blocks (multiple of 8 for XCD swizzle)
  gemm256<0><<<1024, 512, 0, stream>>>(xb, WqT, bqp, QKws, 16, 65536, 1048576L,
                                       65536L);
  // V projection, swapped operands -> V^T per head: M=2048 (n'), N=16384 tokens
  // grid 8 m-tiles x 64 n-tiles = 512 blocks
  gemm256<1><<<512, 512, 0, stream>>>(WvT, xb, bvp, VTs, 64, 65536, 65536L,
                                      524288L);

  attn_fused4<<<dim3(8, 64), 512, 0, stream>>>(QKws, VTs, QKws);

  // output projection: M=16384, N=256, K=2048 (head-blocked A), fp32 out + bo
  gemm128<2><<<dim3(2, 128), 256, 0, stream>>>(QKws, WoT, bo, d_out, 2048,
                                               1048576, 65536, 2048, 65536L, 0L);
}

// Round 6
// 233.819 us; speedup vs baseline: 1.2864x; 1.0124x over previous
//
#include <hip/hip_runtime.h>
#include <hip/hip_fp16.h>

typedef _Float16 f16;
typedef _Float16 f16x8 __attribute__((ext_vector_type(8)));
typedef _Float16 f16x4 __attribute__((ext_vector_type(4)));
typedef _Float16 f16x2 __attribute__((ext_vector_type(2)));
typedef float f32x4 __attribute__((ext_vector_type(4)));
typedef float f32x16 __attribute__((ext_vector_type(16)));

#define GLB(p) ((const __attribute__((address_space(1))) void*)(p))
#define LDSP(p) ((__attribute__((address_space(3))) void*)(p))

__device__ __forceinline__ void gload16(const void* g, void* l) {
  __builtin_amdgcn_global_load_lds(GLB(g), LDSP(l), 16, 0, 0);
}

// counted vmcnt wait (immediate) + compiler-fenced barrier
#define VMW(n) asm volatile("s_waitcnt vmcnt(" #n ")" ::: "memory")
__device__ __forceinline__ void barrier_fenced() {
  asm volatile("" ::: "memory");
  __builtin_amdgcn_s_barrier();
  asm volatile("" ::: "memory");
}

// ---------------- prep ----------------
__global__ __launch_bounds__(256) void prep_x(const float* __restrict__ x,
                                              f16* __restrict__ xb) {
  int i = (blockIdx.x * 256 + threadIdx.x) * 4;
  float4 v = *(const float4*)(x + i);
  f16x4 o = {(f16)v.x, (f16)v.y, (f16)v.z, (f16)v.w};
  *(f16x4*)(xb + i) = o;
}

// WT'[n'][c] = W[c][(n'&255)*8 + (n'>>8)]   (n' = h*256+d, src n = d*8+h)
// WoT'[dm][n'] = Wo[(d*8+h)*256 + dm]
__global__ __launch_bounds__(256) void prep_w(
    const float* __restrict__ Wq, const float* __restrict__ Wk,
    const float* __restrict__ Wv, const float* __restrict__ Wo,
    const float* __restrict__ bq, const float* __restrict__ bk,
    const float* __restrict__ bv,
    f16* __restrict__ WqT, f16* __restrict__ WkT, f16* __restrict__ WvT,
    f16* __restrict__ WoT, float* __restrict__ bqp, float* __restrict__ bkp,
    float* __restrict__ bvp) {
  int i = blockIdx.x * 256 + threadIdx.x;  // 0..524287
  {
    int np = i >> 8, c = i & 255;
    int src = c * 2048 + (np & 255) * 8 + (np >> 8);
    WqT[i] = (f16)Wq[src];
    WkT[i] = (f16)Wk[src];
    WvT[i] = (f16)Wv[src];
  }
  {
    int dm = i >> 11, np = i & 2047;
    WoT[i] = (f16)Wo[((np & 255) * 8 + (np >> 8)) * 256 + dm];
  }
  if (i < 2048) {
    int src = (i & 255) * 8 + (i >> 8);
    bqp[i] = bq[src];
    bkp[i] = bk[src];
    bvp[i] = bv[src];
  }
}

// ---------------- 256x256-tile fp16 GEMM, 32x32x16 MFMA, K=256 fixed ----------------
// A(m,k) elem = (m>>8)*aq1 + (m&255)*256 + k      (K-innermost)
// B(n,k) elem = n*256 + k
// C(m,n) elem = (m>>8)*cp1 + (m&255)*256 + (n>>8)*cp3 + (n&255)   (f16)
// OUTMODE: 0 = col bias (bias[n]), 1 = row bias (bias[m])
template <int OUTMODE>
__global__ __launch_bounds__(512, 2) void gemm256(
    const f16* __restrict__ A, const f16* __restrict__ B,
    const float* __restrict__ bias, f16* __restrict__ C, int NT, int aq1,
    long cp1, long cp3) {
  __shared__ __align__(16) char smem[98304];
  const int tid = threadIdx.x;
  const int lane = tid & 63;
  const int wid = tid >> 6;
  const int l31 = lane & 31, lh = lane >> 5;  // lh selects k-half of a fragment
  const int wr = wid >> 2, wc = wid & 3;      // wave grid 2(M) x 4(N)
  // XCD-bijective swizzle (grid size is a multiple of 8)
  const int nwg = gridDim.x, bid = blockIdx.x;
  const int sw = (bid & 7) * (nwg >> 3) + (bid >> 3);
  const int n0 = (sw % NT) * 256, m0 = (sw / NT) * 256;

  auto stageA = [&](int buf, int kt) {
#pragma unroll
    for (int r = 0; r < 2; ++r) {
      int flat = r * 8192 + tid * 16;
      int row = flat >> 6;
      int kk = kt * 32 + (((flat ^ (((row >> 1) & 3) << 4)) & 63) >> 1);
      int m = m0 + row;
      gload16(A + (long)(m >> 8) * aq1 + (long)(m & 255) * 256 + kk,
              smem + buf * 16384 + flat);
    }
  };
  auto stageB = [&](int buf, int kt) {
#pragma unroll
    for (int r = 0; r < 2; ++r) {
      int flat = r * 8192 + tid * 16;
      int row = flat >> 6;
      int kk = kt * 32 + (((flat ^ (((row >> 1) & 3) << 4)) & 63) >> 1);
      gload16(B + (long)(n0 + row) * 256 + kk,
              smem + 49152 + buf * 16384 + flat);
    }
  };
  auto ldA = [&](int buf, int row, int kf) -> f16x8 {
    int cb = kf * 32 + lh * 16;
    return *(const f16x8*)(smem + buf * 16384 + row * 64 +
                           (cb ^ (((row >> 1) & 3) << 4)));
  };
  auto ldB = [&](int buf, int row, int kf) -> f16x8 {
    int cb = kf * 32 + lh * 16;
    return *(const f16x8*)(smem + 49152 + buf * 16384 + row * 64 +
                           (cb ^ (((row >> 1) & 3) << 4)));
  };

  f32x16 acc[4][2] = {};
  stageA(0, 0);
  stageB(0, 0);
  stageA(1, 1);
  stageB(1, 1);
#pragma unroll
  for (int t = 0; t < 8; ++t) {
    if (t < 7) {
      VMW(4);  // tile t landed; tile t+1 (4 loads) stays in flight
    } else {
      VMW(0);
    }
    barrier_fenced();  // all waves' tile-t loads visible; buf (t+2)%3 free
    const int buf = t % 3;
    const int sb = (t + 2) % 3;
    // ---- k-phase 0 ----
    f16x8 a[4], b[2];
#pragma unroll
    for (int mi = 0; mi < 4; ++mi) a[mi] = ldA(buf, wr * 128 + mi * 32 + l31, 0);
#pragma unroll
    for (int ni = 0; ni < 2; ++ni) b[ni] = ldB(buf, wc * 64 + ni * 32 + l31, 0);
    if (t < 6) stageA(sb, t + 2);
    __builtin_amdgcn_s_setprio(1);
#pragma unroll
    for (int mi = 0; mi < 4; ++mi)
#pragma unroll
      for (int ni = 0; ni < 2; ++ni)
        acc[mi][ni] = __builtin_amdgcn_mfma_f32_32x32x16_f16(a[mi], b[ni],
                                                             acc[mi][ni], 0, 0, 0);
    __builtin_amdgcn_s_setprio(0);
    // ---- k-phase 1 ----
#pragma unroll
    for (int mi = 0; mi < 4; ++mi) a[mi] = ldA(buf, wr * 128 + mi * 32 + l31, 1);
#pragma unroll
    for (int ni = 0; ni < 2; ++ni) b[ni] = ldB(buf, wc * 64 + ni * 32 + l31, 1);
    if (t < 6) stageB(sb, t + 2);
    __builtin_amdgcn_s_setprio(1);
#pragma unroll
    for (int mi = 0; mi < 4; ++mi)
#pragma unroll
      for (int ni = 0; ni < 2; ++ni)
        acc[mi][ni] = __builtin_amdgcn_mfma_f32_32x32x16_f16(a[mi], b[ni],
                                                             acc[mi][ni], 0, 0, 0);
    __builtin_amdgcn_s_setprio(0);
  }

  // epilogue: C/D layout col=lane&31, row=(reg&3)+8*(reg>>2)+4*(lane>>5)
#pragma unroll
  for (int mi = 0; mi < 4; ++mi)
#pragma unroll
    for (int ni = 0; ni < 2; ++ni)
#pragma unroll
      for (int reg = 0; reg < 16; ++reg) {
        int m = m0 + wr * 128 + mi * 32 + (reg & 3) + 8 * (reg >> 2) + 4 * lh;
        int n = n0 + wc * 64 + ni * 32 + l31;
        float v = acc[mi][ni][reg];
        v += (OUTMODE == 1) ? bias[m] : bias[n];
        long off = (long)(m >> 8) * cp1 + (long)(m & 255) * 256 +
                   (long)(n >> 8) * cp3 + (n & 255);
        C[off] = (f16)v;
      }
}

// ---------------- generic 128x128 fp16 GEMM (O-proj; split-K via blockIdx.z) ----
// A(m,k) elem = (m>>8)*aq1 + (m&255)*256 + (k>>8)*aq3 + (k&255)
// B(n,k) elem = n*ldb + k
// C(m,n) elem = (m>>8)*cp1 + (m&255)*256 + (n>>8)*cp3 + (n&255)
// OUTMODE: 0 = f16 out + col bias, 1 = f16 out + row bias, 2 = f32 out + col bias,
//          3 = f32 partial (no bias), z-offset kz*65536 elems
template <int OUTMODE>
__global__ __launch_bounds__(256, 4) void gemm128(
    const f16* __restrict__ A, const f16* __restrict__ B,
    const float* __restrict__ bias, void* __restrict__ Cptr, int K, int aq1,
    int aq3, int ldb, long cp1, long cp3) {
  const int kz = blockIdx.z;
  A += (long)kz * (K >> 8) * (long)aq3;  // K per split is a multiple of 256
  B += (long)kz * K;
  __shared__ f16 As[4][128 * 32];
  __shared__ f16 Bs[4][128 * 32];
  const int tid = threadIdx.x;
  const int m0 = blockIdx.y * 128;
  const int n0 = blockIdx.x * 128;
  const int lane = tid & 63, wid = tid >> 6;
  const int l15 = lane & 15, lg = lane >> 4;
  const int wm = (wid >> 1) * 64, wn = (wid & 1) * 64;

  f32x4 acc[4][4] = {};

  auto stage = [&](int buf, int kt) {
    int k0 = kt * 32;
#pragma unroll
    for (int r = 0; r < 2; ++r) {
      int flat = r * 4096 + tid * 16;  // byte offset within 8KB tile
      int row = flat >> 6;             // 64B per row
      int kk = k0 + ((flat & 63) >> 1);
      int m = m0 + row;
      gload16(A + (long)(m >> 8) * aq1 + (long)(m & 255) * 256 +
                  (long)(kk >> 8) * aq3 + (kk & 255),
              (char*)(&As[buf][0]) + flat);
      int n = n0 + row;
      gload16(B + (long)n * ldb + kk, (char*)(&Bs[buf][0]) + flat);
    }
  };

  auto compute = [&](int t) {
    const f16* as = &As[t & 3][0];
    const f16* bs = &Bs[t & 3][0];
    f16x8 af[4], bf[4];
#pragma unroll
    for (int i = 0; i < 4; ++i)
      af[i] = *(const f16x8*)(as + (wm + i * 16 + l15) * 32 + lg * 8);
#pragma unroll
    for (int j = 0; j < 4; ++j)
      bf[j] = *(const f16x8*)(bs + (wn + j * 16 + l15) * 32 + lg * 8);
#pragma unroll
    for (int i = 0; i < 4; ++i)
#pragma unroll
      for (int j = 0; j < 4; ++j)
        acc[i][j] =
            __builtin_amdgcn_mfma_f32_16x16x32_f16(af[i], bf[j], acc[i][j], 0, 0, 0);
  };

  const int T = K >> 5;  // always >= 8
  stage(0, 0);
  stage(1, 1);
  for (int t = 0; t < T - 2; ++t) {
    stage((t + 2) & 3, t + 2);
    VMW(8);   // tiles {t+1, t+2} (4 loads each) may remain in flight
    barrier_fenced();
    compute(t);
  }
  VMW(4);  // only tile T-1 in flight
  barrier_fenced();
  compute(T - 2);
  VMW(0);
  barrier_fenced();
  compute(T - 1);

#pragma unroll
  for (int i = 0; i < 4; ++i) {
#pragma unroll
    for (int j = 0; j < 4; ++j) {
#pragma unroll
      for (int jj = 0; jj < 4; ++jj) {
        int m = m0 + wm + i * 16 + lg * 4 + jj;
        int n = n0 + wn + j * 16 + l15;
        float v = acc[i][j][jj];
        if (OUTMODE != 3) v += (OUTMODE == 1) ? bias[m] : bias[n];
        long off = (long)(m >> 8) * cp1 + (long)(m & 255) * 256 +
                   (long)(n >> 8) * cp3 + (n & 255);
        if (OUTMODE == 3)
          ((float*)Cptr)[off + (long)kz * 65536] = v;
        else if (OUTMODE == 2)
          ((float*)Cptr)[off] = v;
        else
          ((f16*)Cptr)[off] = (f16)v;
      }
    }
  }
}

// sum 2 split-K partials + bias -> d_out (fp32)
__global__ __launch_bounds__(256) void reduce_out(const float* __restrict__ P,
                                                  const float* __restrict__ bo,
                                                  float* __restrict__ out) {
  int i = (blockIdx.x * 256 + threadIdx.x) * 4;  // 4.19M fp32 total
  int n = i & 255, tok = (i >> 8) & 255, bc = i >> 16;
  long b = (long)bc * 524288 + (long)tok * 256 + n;
  float4 a0 = *(const float4*)(P + b);
  float4 a1 = *(const float4*)(P + b + 65536);
  float4 bb = *(const float4*)(bo + n);
  float4 r = {a0.x + a1.x + bb.x, a0.y + a1.y + bb.y, a0.z + a1.z + bb.z,
              a0.w + a1.w + bb.w};
  *(float4*)(out + i) = r;
}

// ---------------- fused attention v4 (unchanged) ----------------
__global__ __launch_bounds__(512, 2) void attn_fused4(const f16* __restrict__ QK,
                                                      const f16* __restrict__ Vw,
                                                      f16* __restrict__ Ow) {
  __shared__ __align__(16) char smem[163840];
  const int tid = threadIdx.x;
  const int lane = tid & 63, wid = tid >> 6;
  const int l15 = lane & 15, lg = lane >> 4;
  const int h = blockIdx.x, bc = blockIdx.y;
  const long base = (long)bc * 1048576 + (long)h * 65536;  // Q slice in interleaved QK
  const f16* Qh = QK + base;
  const f16* Kh = QK + base + 524288;
  const f16* Vh = Vw + (long)bc * 524288 + (long)h * 65536;  // V^T [d][q]
  const int w32 = wid * 32;

  auto stagePair = [&](int t) {
    int buf = t & 3;
#pragma unroll
    for (int r = 0; r < 2; ++r) {
      int flat = r * 8192 + tid * 16;
      int row = flat >> 6;
      int kk = t * 32 + (((flat ^ (((row >> 1) & 3) << 4)) & 63) >> 1);
      gload16(Qh + (long)row * 256 + kk, smem + buf * 16384 + flat);
      gload16(Kh + (long)row * 256 + kk, smem + 65536 + buf * 16384 + flat);
    }
  };
  auto stageV = [&](int st) {
    int flat = tid * 16;
    int row = flat >> 6;  // 0..127
    int kk = (st >> 1) * 32 + (((flat ^ (((row >> 1) & 3) << 4)) & 63) >> 1);
    gload16(Vh + (long)((st & 1) * 128 + row) * 256 + kk,
            smem + 131072 + (st & 3) * 8192 + flat);
  };
  auto ldQ = [&](int t, int row, int koff) -> f16x8 {
    return *(const f16x8*)(smem + (t & 3) * 16384 + row * 64 +
                           (koff ^ (((row >> 1) & 3) << 4)));
  };
  auto ldK = [&](int t, int row, int koff) -> f16x8 {
    return *(const f16x8*)(smem + 65536 + (t & 3) * 16384 + row * 64 +
                           (koff ^ (((row >> 1) & 3) << 4)));
  };
  auto ldV = [&](int st, int row, int koff) -> f16x8 {
    return *(const f16x8*)(smem + 131072 + (st & 3) * 8192 + row * 64 +
                           (koff ^ (((row >> 1) & 3) << 4)));
  };

  // ---------- phase A: S = Q K^T ----------
  f32x4 acc[2][16] = {};
  stagePair(0);
  stagePair(1);
#pragma unroll
  for (int t = 0; t < 8; ++t) {
    if (t < 6) {
      stagePair(t + 2);
      VMW(8);
    } else if (t == 6) {
      stageV(0);
      stageV(1);
      VMW(6);
    } else {
      VMW(2);
    }
    barrier_fenced();
    f16x8 af[2];
#pragma unroll
    for (int i = 0; i < 2; ++i) af[i] = ldQ(t, w32 + i * 16 + l15, lg * 16);
    __builtin_amdgcn_s_setprio(1);
#pragma unroll
    for (int j = 0; j < 16; ++j) {
      f16x8 b = ldK(t, j * 16 + l15, lg * 16);
#pragma unroll
      for (int i = 0; i < 2; ++i)
        acc[i][j] =
            __builtin_amdgcn_mfma_f32_16x16x32_f16(af[i], b, acc[i][j], 0, 0, 0);
    }
    __builtin_amdgcn_s_setprio(0);
  }
  barrier_fenced();  // all waves' Q/K LDS reads done; P may overwrite region

  // ---------- softmax over 256 cols (rows wave-local) ----------
  const float SCL = 0.0625f * 1.44269504089f;
  float inv[2][4];
#pragma unroll
  for (int i = 0; i < 2; ++i) {
#pragma unroll
    for (int jj = 0; jj < 4; ++jj) {
      float m_ = acc[i][0][jj];
#pragma unroll
      for (int f = 1; f < 16; ++f) m_ = fmaxf(m_, acc[i][f][jj]);
#pragma unroll
      for (int off = 1; off < 16; off <<= 1) m_ = fmaxf(m_, __shfl_xor(m_, off, 64));
      float s_ = 0.f;
#pragma unroll
      for (int f = 0; f < 16; ++f) {
        float e = __builtin_exp2f((acc[i][f][jj] - m_) * SCL);
        acc[i][f][jj] = e;
        s_ += e;
      }
#pragma unroll
      for (int off = 1; off < 16; off <<= 1) s_ += __shfl_xor(s_, off, 64);
      inv[i][jj] = 1.f / s_;
    }
  }

  // write P [256 rows][256 cols] f16 @smem[0..131072), swizzled
#pragma unroll
  for (int i = 0; i < 2; ++i)
#pragma unroll
    for (int f = 0; f < 16; ++f)
#pragma unroll
      for (int jj = 0; jj < 4; ++jj) {
        int row = w32 + i * 16 + lg * 4 + jj;
        int colb = (f * 16 + l15) * 2;
        *(f16*)(smem + row * 512 + (colb ^ ((row & 7) << 4))) =
            (f16)(acc[i][f][jj] * inv[i][jj]);
      }

  // ---------- phase B: O = P V over 16 V sub-tiles ----------
  f32x4 oacc[2][16] = {};
#pragma unroll
  for (int st = 0; st < 16; ++st) {
    if (st < 14) {
      stageV(st + 2);
      VMW(2);
    } else if (st == 14) {
      VMW(1);
    } else {
      VMW(0);
    }
    barrier_fenced();
    const int t = st >> 1, dh = st & 1;
    f16x8 pf[2];
#pragma unroll
    for (int i = 0; i < 2; ++i) {
      int row = w32 + i * 16 + l15;
      pf[i] = *(const f16x8*)(smem + row * 512 +
                              ((t * 64 + lg * 16) ^ ((row & 7) << 4)));
    }
    __builtin_amdgcn_s_setprio(1);
#pragma unroll
    for (int jj = 0; jj < 8; ++jj) {
      f16x8 b = ldV(st, jj * 16 + l15, lg * 16);
      const int j = dh * 8 + jj;
#pragma unroll
      for (int i = 0; i < 2; ++i)
        oacc[i][j] =
            __builtin_amdgcn_mfma_f32_16x16x32_f16(pf[i], b, oacc[i][j], 0, 0, 0);
    }
    __builtin_amdgcn_s_setprio(0);
  }

  // write O tile into the Q slice (aliased; this block's Q reads are done)
#pragma unroll
  for (int i = 0; i < 2; ++i)
#pragma unroll
    for (int f = 0; f < 16; ++f)
#pragma unroll
      for (int jj = 0; jj < 4; ++jj) {
        int q = w32 + i * 16 + lg * 4 + jj;
        int d = f * 16 + l15;
        Ow[base + (long)q * 256 + d] = (f16)(oacc[i][f][jj]);
      }
}

// ---------------- launch ----------------
// ws layout (bytes):
//   xb    @ 0         8388608   fp16 x [16384][256]
//   WqT   @ 8388608   1048576   [2048][256] permuted-transposed   (contiguous
//   WkT   @ 9437184   1048576    with WqT -> fused QK B operand [4096][256])
//   WvT   @ 10485760  1048576
//   WoT   @ 11534336  1048576   [256][2048] permuted-transposed
//   bqp   @ 12582912  8192      (contiguous with bkp -> fused bias [4096])
//   bkp   @ 12591104  8192
//   bvp   @ 12599296  8192
//   QK    @ 12607488  134217728 interleaved [bc][qk][h][q][d] f16
//            qk=0 half: Q, overwritten in place by attn O
//            qk=1 half: K; dead after attn -> reused for O-proj fp32 partials
//              partial(z,bc,tok,n) = f32[(QK+1MB per-bc) + bc*2MB]: off32 =
//              bc*524288 + 262144 + z*65536 + tok*256 + n
//   VT    @ +134217728 67108864 [bc][h][d][q] f16
extern "C" void kernel_launch(void* const* d_in, const int* in_sizes, int n_in,
                              void* d_out, int out_size, void* d_ws,
                              size_t ws_size, hipStream_t stream) {
  const float* x = (const float*)d_in[0];
  const float* Wq = (const float*)d_in[1];
  const float* bq = (const float*)d_in[2];
  const float* Wk = (const float*)d_in[3];
  const float* bk = (const float*)d_in[4];
  const float* Wv = (const float*)d_in[5];
  const float* bv = (const float*)d_in[6];
  const float* Wo = (const float*)d_in[7];
  const float* bo = (const float*)d_in[8];

  char* ws = (char*)d_ws;
  f16* xb = (f16*)(ws + 0);
  f16* WqT = (f16*)(ws + 8388608);
  f16* WkT = (f16*)(ws + 9437184);
  f16* WvT = (f16*)(ws + 10485760);
  f16* WoT = (f16*)(ws + 11534336);
  float* bqp = (float*)(ws + 12582912);
  float* bkp = (float*)(ws + 12591104);
  float* bvp = (float*)(ws + 12599296);
  f16* QKws = (f16*)(ws + 12607488);
  f16* VTs = (f16*)(ws + 12607488 + 134217728L);
  // O-proj fp32 partials live in the dead K half (qk=1) of QK ws
  float* Opart = (float*)(ws + 12607488 + 1048576);  // per-bc stride 524288 f32
  if (ws_size < 12607488ull + 134217728ull + 67108864ull) return;  // ~204MB

  prep_x<<<4096, 256, 0, stream>>>(x, xb);
  prep_w<<<2048, 256, 0, stream>>>(Wq, Wk, Wv, Wo, bq, bk, bv, WqT, WkT, WvT,
                                   WoT, bqp, bkp, bvp);

  // fused Q+K projection: M=16384 tokens, N=4096 (qk*2048 + h*256 + d), K=256
  gemm256<0><<<1024, 512, 0, stream>>>(xb, WqT, bqp, QKws, 16, 65536, 1048576L,
                                       65536L);
  // V projection, swapped operands -> V^T per head: M=2048 (n'), N=16384 tokens
  gemm256<1><<<512, 512, 0, stream>>>(WvT, xb, bvp, VTs, 64, 65536, 65536L,
                                      524288L);

  attn_fused4<<<dim3(8, 64), 512, 0, stream>>>(QKws, VTs, QKws);

  // output projection, split-K=2 (1024 each): M=16384, N=256, fp32 partials
  gemm128<3><<<dim3(2, 128, 2), 256, 0, stream>>>(QKws, WoT, nullptr, Opart,
                                                  1024, 1048576, 65536, 2048,
                                                  524288L, 0L);
  // partial0 + partial1 + bo -> d_out
  reduce_out<<<4096, 256, 0, stream>>>(Opart, bo, (float*)d_out);
}

// Round 7
// 232.039 us; speedup vs baseline: 1.2962x; 1.0077x over previous
//
#include <hip/hip_runtime.h>
#include <hip/hip_fp16.h>

typedef _Float16 f16;
typedef _Float16 f16x8 __attribute__((ext_vector_type(8)));
typedef _Float16 f16x4 __attribute__((ext_vector_type(4)));
typedef _Float16 f16x2 __attribute__((ext_vector_type(2)));
typedef float f32x4 __attribute__((ext_vector_type(4)));
typedef float f32x16 __attribute__((ext_vector_type(16)));

#define GLB(p) ((const __attribute__((address_space(1))) void*)(p))
#define LDSP(p) ((__attribute__((address_space(3))) void*)(p))

__device__ __forceinline__ void gload16(const void* g, void* l) {
  __builtin_amdgcn_global_load_lds(GLB(g), LDSP(l), 16, 0, 0);
}

// counted vmcnt wait (immediate) + compiler-fenced barrier
#define VMW(n) asm volatile("s_waitcnt vmcnt(" #n ")" ::: "memory")
__device__ __forceinline__ void barrier_fenced() {
  asm volatile("" ::: "memory");
  __builtin_amdgcn_s_barrier();
  asm volatile("" ::: "memory");
}

// ---------------- prep ----------------
__global__ __launch_bounds__(256) void prep_x(const float* __restrict__ x,
                                              f16* __restrict__ xb) {
  int i = (blockIdx.x * 256 + threadIdx.x) * 4;
  float4 v = *(const float4*)(x + i);
  f16x4 o = {(f16)v.x, (f16)v.y, (f16)v.z, (f16)v.w};
  *(f16x4*)(xb + i) = o;
}

// WT'[n'][c] = W[c][(n'&255)*8 + (n'>>8)]   (n' = h*256+d, src n = d*8+h)
// WoT'[dm][n'] = Wo[(d*8+h)*256 + dm]
__global__ __launch_bounds__(256) void prep_w(
    const float* __restrict__ Wq, const float* __restrict__ Wk,
    const float* __restrict__ Wv, const float* __restrict__ Wo,
    const float* __restrict__ bq, const float* __restrict__ bk,
    const float* __restrict__ bv,
    f16* __restrict__ WqT, f16* __restrict__ WkT, f16* __restrict__ WvT,
    f16* __restrict__ WoT, float* __restrict__ bqp, float* __restrict__ bkp,
    float* __restrict__ bvp) {
  int i = blockIdx.x * 256 + threadIdx.x;  // 0..524287
  {
    int np = i >> 8, c = i & 255;
    int src = c * 2048 + (np & 255) * 8 + (np >> 8);
    WqT[i] = (f16)Wq[src];
    WkT[i] = (f16)Wk[src];
    WvT[i] = (f16)Wv[src];
  }
  {
    int dm = i >> 11, np = i & 2047;
    WoT[i] = (f16)Wo[((np & 255) * 8 + (np >> 8)) * 256 + dm];
  }
  if (i < 2048) {
    int src = (i & 255) * 8 + (i >> 8);
    bqp[i] = bq[src];
    bkp[i] = bk[src];
    bvp[i] = bv[src];
  }
}

// ---------------- 256x256-tile fp16 GEMM, 32x32x16 MFMA, K=256 fixed ----------------
// 8-phase-style schedule: per K-tile (BK=32) two phases, each
// {JIT frag ds_reads, issue half of tile t+2 staging, barrier, MFMA cluster,
//  barrier}; counted VMW(4) once per tile (never drains in main loop).
// A(m,k) elem = (m>>8)*aq1 + (m&255)*256 + k      (K-innermost)
// B(n,k) elem = n*256 + k
// C(m,n) elem = (m>>8)*cp1 + (m&255)*256 + (n>>8)*cp3 + (n&255)   (f16)
// OUTMODE: 0 = col bias (bias[n]), 1 = row bias (bias[m])
template <int OUTMODE>
__global__ __launch_bounds__(512, 2) void gemm256(
    const f16* __restrict__ A, const f16* __restrict__ B,
    const float* __restrict__ bias, f16* __restrict__ C, int NT, int aq1,
    long cp1, long cp3) {
  __shared__ __align__(16) char smem[98304];
  const int tid = threadIdx.x;
  const int lane = tid & 63;
  const int wid = tid >> 6;
  const int l31 = lane & 31, lh = lane >> 5;  // lh selects k-half of a fragment
  const int wr = wid >> 2, wc = wid & 3;      // wave grid 2(M) x 4(N)
  // XCD-bijective swizzle (grid size is a multiple of 8)
  const int nwg = gridDim.x, bid = blockIdx.x;
  const int sw = (bid & 7) * (nwg >> 3) + (bid >> 3);
  const int n0 = (sw % NT) * 256, m0 = (sw / NT) * 256;

  auto stageA = [&](int buf, int kt) {
#pragma unroll
    for (int r = 0; r < 2; ++r) {
      int flat = r * 8192 + tid * 16;
      int row = flat >> 6;
      int kk = kt * 32 + (((flat ^ (((row >> 1) & 3) << 4)) & 63) >> 1);
      int m = m0 + row;
      gload16(A + (long)(m >> 8) * aq1 + (long)(m & 255) * 256 + kk,
              smem + buf * 16384 + flat);
    }
  };
  auto stageB = [&](int buf, int kt) {
#pragma unroll
    for (int r = 0; r < 2; ++r) {
      int flat = r * 8192 + tid * 16;
      int row = flat >> 6;
      int kk = kt * 32 + (((flat ^ (((row >> 1) & 3) << 4)) & 63) >> 1);
      gload16(B + (long)(n0 + row) * 256 + kk,
              smem + 49152 + buf * 16384 + flat);
    }
  };
  auto ldA = [&](int buf, int row, int kf) -> f16x8 {
    int cb = kf * 32 + lh * 16;
    return *(const f16x8*)(smem + buf * 16384 + row * 64 +
                           (cb ^ (((row >> 1) & 3) << 4)));
  };
  auto ldB = [&](int buf, int row, int kf) -> f16x8 {
    int cb = kf * 32 + lh * 16;
    return *(const f16x8*)(smem + 49152 + buf * 16384 + row * 64 +
                           (cb ^ (((row >> 1) & 3) << 4)));
  };

  f32x16 acc[4][2] = {};
  stageA(0, 0);
  stageB(0, 0);
  stageA(1, 1);
  stageB(1, 1);
  VMW(4);            // tile 0 landed; tile 1 (4 loads) in flight
  barrier_fenced();  // tile 0 visible to all waves
#pragma unroll
  for (int t = 0; t < 8; ++t) {
    const int buf = t % 3;
    const int sb = (t + 2) % 3;  // holds tile t-1, fully consumed before t began
    f16x8 a[4], b[2];
    // ---- phase 0 (k-step 0) ----
#pragma unroll
    for (int mi = 0; mi < 4; ++mi) a[mi] = ldA(buf, wr * 128 + mi * 32 + l31, 0);
#pragma unroll
    for (int ni = 0; ni < 2; ++ni) b[ni] = ldB(buf, wc * 64 + ni * 32 + l31, 0);
    if (t < 6) stageA(sb, t + 2);
    barrier_fenced();
    __builtin_amdgcn_s_setprio(1);
#pragma unroll
    for (int mi = 0; mi < 4; ++mi)
#pragma unroll
      for (int ni = 0; ni < 2; ++ni)
        acc[mi][ni] = __builtin_amdgcn_mfma_f32_32x32x16_f16(a[mi], b[ni],
                                                             acc[mi][ni], 0, 0, 0);
    __builtin_amdgcn_s_setprio(0);
    barrier_fenced();
    // ---- phase 1 (k-step 1) ----
#pragma unroll
    for (int mi = 0; mi < 4; ++mi) a[mi] = ldA(buf, wr * 128 + mi * 32 + l31, 1);
#pragma unroll
    for (int ni = 0; ni < 2; ++ni) b[ni] = ldB(buf, wc * 64 + ni * 32 + l31, 1);
    if (t < 6) stageB(sb, t + 2);
    barrier_fenced();
    __builtin_amdgcn_s_setprio(1);
#pragma unroll
    for (int mi = 0; mi < 4; ++mi)
#pragma unroll
      for (int ni = 0; ni < 2; ++ni)
        acc[mi][ni] = __builtin_amdgcn_mfma_f32_32x32x16_f16(a[mi], b[ni],
                                                             acc[mi][ni], 0, 0, 0);
    __builtin_amdgcn_s_setprio(0);
    // end-of-tile gate: tile t+1 must be visible entering iteration t+1
    if (t < 6) {
      VMW(4);  // waits tile t+1; leaves tile t+2's 4 loads in flight
    } else if (t == 6) {
      VMW(0);  // tile 7 landed (no tile 9 exists)
    }
    barrier_fenced();
  }

  // epilogue: C/D layout col=lane&31, row=(reg&3)+8*(reg>>2)+4*(lane>>5)
#pragma unroll
  for (int mi = 0; mi < 4; ++mi)
#pragma unroll
    for (int ni = 0; ni < 2; ++ni)
#pragma unroll
      for (int reg = 0; reg < 16; ++reg) {
        int m = m0 + wr * 128 + mi * 32 + (reg & 3) + 8 * (reg >> 2) + 4 * lh;
        int n = n0 + wc * 64 + ni * 32 + l31;
        float v = acc[mi][ni][reg];
        v += (OUTMODE == 1) ? bias[m] : bias[n];
        long off = (long)(m >> 8) * cp1 + (long)(m & 255) * 256 +
                   (long)(n >> 8) * cp3 + (n & 255);
        C[off] = (f16)v;
      }
}

// ---------------- generic 128x128 fp16 GEMM (O-proj; split-K via blockIdx.z) ----
// A(m,k) elem = (m>>8)*aq1 + (m&255)*256 + (k>>8)*aq3 + (k&255)
// B(n,k) elem = n*ldb + k
// C(m,n) elem = (m>>8)*cp1 + (m&255)*256 + (n>>8)*cp3 + (n&255)
// OUTMODE: 0 = f16 out + col bias, 1 = f16 out + row bias, 2 = f32 out + col bias,
//          3 = f32 partial (no bias), z-offset kz*65536 elems
template <int OUTMODE>
__global__ __launch_bounds__(256, 4) void gemm128(
    const f16* __restrict__ A, const f16* __restrict__ B,
    const float* __restrict__ bias, void* __restrict__ Cptr, int K, int aq1,
    int aq3, int ldb, long cp1, long cp3) {
  const int kz = blockIdx.z;
  A += (long)kz * (K >> 8) * (long)aq3;  // K per split is a multiple of 256
  B += (long)kz * K;
  __shared__ f16 As[4][128 * 32];
  __shared__ f16 Bs[4][128 * 32];
  const int tid = threadIdx.x;
  const int m0 = blockIdx.y * 128;
  const int n0 = blockIdx.x * 128;
  const int lane = tid & 63, wid = tid >> 6;
  const int l15 = lane & 15, lg = lane >> 4;
  const int wm = (wid >> 1) * 64, wn = (wid & 1) * 64;

  f32x4 acc[4][4] = {};

  auto stage = [&](int buf, int kt) {
    int k0 = kt * 32;
#pragma unroll
    for (int r = 0; r < 2; ++r) {
      int flat = r * 4096 + tid * 16;  // byte offset within 8KB tile
      int row = flat >> 6;             // 64B per row
      int kk = k0 + ((flat & 63) >> 1);
      int m = m0 + row;
      gload16(A + (long)(m >> 8) * aq1 + (long)(m & 255) * 256 +
                  (long)(kk >> 8) * aq3 + (kk & 255),
              (char*)(&As[buf][0]) + flat);
      int n = n0 + row;
      gload16(B + (long)n * ldb + kk, (char*)(&Bs[buf][0]) + flat);
    }
  };

  auto compute = [&](int t) {
    const f16* as = &As[t & 3][0];
    const f16* bs = &Bs[t & 3][0];
    f16x8 af[4], bf[4];
#pragma unroll
    for (int i = 0; i < 4; ++i)
      af[i] = *(const f16x8*)(as + (wm + i * 16 + l15) * 32 + lg * 8);
#pragma unroll
    for (int j = 0; j < 4; ++j)
      bf[j] = *(const f16x8*)(bs + (wn + j * 16 + l15) * 32 + lg * 8);
#pragma unroll
    for (int i = 0; i < 4; ++i)
#pragma unroll
      for (int j = 0; j < 4; ++j)
        acc[i][j] =
            __builtin_amdgcn_mfma_f32_16x16x32_f16(af[i], bf[j], acc[i][j], 0, 0, 0);
  };

  const int T = K >> 5;  // always >= 8
  stage(0, 0);
  stage(1, 1);
  for (int t = 0; t < T - 2; ++t) {
    stage((t + 2) & 3, t + 2);
    VMW(8);   // tiles {t+1, t+2} (4 loads each) may remain in flight
    barrier_fenced();
    compute(t);
  }
  VMW(4);  // only tile T-1 in flight
  barrier_fenced();
  compute(T - 2);
  VMW(0);
  barrier_fenced();
  compute(T - 1);

#pragma unroll
  for (int i = 0; i < 4; ++i) {
#pragma unroll
    for (int j = 0; j < 4; ++j) {
#pragma unroll
      for (int jj = 0; jj < 4; ++jj) {
        int m = m0 + wm + i * 16 + lg * 4 + jj;
        int n = n0 + wn + j * 16 + l15;
        float v = acc[i][j][jj];
        if (OUTMODE != 3) v += (OUTMODE == 1) ? bias[m] : bias[n];
        long off = (long)(m >> 8) * cp1 + (long)(m & 255) * 256 +
                   (long)(n >> 8) * cp3 + (n & 255);
        if (OUTMODE == 3)
          ((float*)Cptr)[off + (long)kz * 65536] = v;
        else if (OUTMODE == 2)
          ((float*)Cptr)[off] = v;
        else
          ((f16*)Cptr)[off] = (f16)v;
      }
    }
  }
}

// sum 2 split-K partials + bias -> d_out (fp32)
__global__ __launch_bounds__(256) void reduce_out(const float* __restrict__ P,
                                                  const float* __restrict__ bo,
                                                  float* __restrict__ out) {
  int i = (blockIdx.x * 256 + threadIdx.x) * 4;  // 4.19M fp32 total
  int n = i & 255, tok = (i >> 8) & 255, bc = i >> 16;
  long b = (long)bc * 524288 + (long)tok * 256 + n;
  float4 a0 = *(const float4*)(P + b);
  float4 a1 = *(const float4*)(P + b + 65536);
  float4 bb = *(const float4*)(bo + n);
  float4 r = {a0.x + a1.x + bb.x, a0.y + a1.y + bb.y, a0.z + a1.z + bb.z,
              a0.w + a1.w + bb.w};
  *(float4*)(out + i) = r;
}

// ---------------- fused attention v4 (unchanged) ----------------
__global__ __launch_bounds__(512, 2) void attn_fused4(const f16* __restrict__ QK,
                                                      const f16* __restrict__ Vw,
                                                      f16* __restrict__ Ow) {
  __shared__ __align__(16) char smem[163840];
  const int tid = threadIdx.x;
  const int lane = tid & 63, wid = tid >> 6;
  const int l15 = lane & 15, lg = lane >> 4;
  const int h = blockIdx.x, bc = blockIdx.y;
  const long base = (long)bc * 1048576 + (long)h * 65536;  // Q slice in interleaved QK
  const f16* Qh = QK + base;
  const f16* Kh = QK + base + 524288;
  const f16* Vh = Vw + (long)bc * 524288 + (long)h * 65536;  // V^T [d][q]
  const int w32 = wid * 32;

  auto stagePair = [&](int t) {
    int buf = t & 3;
#pragma unroll
    for (int r = 0; r < 2; ++r) {
      int flat = r * 8192 + tid * 16;
      int row = flat >> 6;
      int kk = t * 32 + (((flat ^ (((row >> 1) & 3) << 4)) & 63) >> 1);
      gload16(Qh + (long)row * 256 + kk, smem + buf * 16384 + flat);
      gload16(Kh + (long)row * 256 + kk, smem + 65536 + buf * 16384 + flat);
    }
  };
  auto stageV = [&](int st) {
    int flat = tid * 16;
    int row = flat >> 6;  // 0..127
    int kk = (st >> 1) * 32 + (((flat ^ (((row >> 1) & 3) << 4)) & 63) >> 1);
    gload16(Vh + (long)((st & 1) * 128 + row) * 256 + kk,
            smem + 131072 + (st & 3) * 8192 + flat);
  };
  auto ldQ = [&](int t, int row, int koff) -> f16x8 {
    return *(const f16x8*)(smem + (t & 3) * 16384 + row * 64 +
                           (koff ^ (((row >> 1) & 3) << 4)));
  };
  auto ldK = [&](int t, int row, int koff) -> f16x8 {
    return *(const f16x8*)(smem + 65536 + (t & 3) * 16384 + row * 64 +
                           (koff ^ (((row >> 1) & 3) << 4)));
  };
  auto ldV = [&](int st, int row, int koff) -> f16x8 {
    return *(const f16x8*)(smem + 131072 + (st & 3) * 8192 + row * 64 +
                           (koff ^ (((row >> 1) & 3) << 4)));
  };

  // ---------- phase A: S = Q K^T ----------
  f32x4 acc[2][16] = {};
  stagePair(0);
  stagePair(1);
#pragma unroll
  for (int t = 0; t < 8; ++t) {
    if (t < 6) {
      stagePair(t + 2);
      VMW(8);
    } else if (t == 6) {
      stageV(0);
      stageV(1);
      VMW(6);
    } else {
      VMW(2);
    }
    barrier_fenced();
    f16x8 af[2];
#pragma unroll
    for (int i = 0; i < 2; ++i) af[i] = ldQ(t, w32 + i * 16 + l15, lg * 16);
    __builtin_amdgcn_s_setprio(1);
#pragma unroll
    for (int j = 0; j < 16; ++j) {
      f16x8 b = ldK(t, j * 16 + l15, lg * 16);
#pragma unroll
      for (int i = 0; i < 2; ++i)
        acc[i][j] =
            __builtin_amdgcn_mfma_f32_16x16x32_f16(af[i], b, acc[i][j], 0, 0, 0);
    }
    __builtin_amdgcn_s_setprio(0);
  }
  barrier_fenced();  // all waves' Q/K LDS reads done; P may overwrite region

  // ---------- softmax over 256 cols (rows wave-local) ----------
  const float SCL = 0.0625f * 1.44269504089f;
  float inv[2][4];
#pragma unroll
  for (int i = 0; i < 2; ++i) {
#pragma unroll
    for (int jj = 0; jj < 4; ++jj) {
      float m_ = acc[i][0][jj];
#pragma unroll
      for (int f = 1; f < 16; ++f) m_ = fmaxf(m_, acc[i][f][jj]);
#pragma unroll
      for (int off = 1; off < 16; off <<= 1) m_ = fmaxf(m_, __shfl_xor(m_, off, 64));
      float s_ = 0.f;
#pragma unroll
      for (int f = 0; f < 16; ++f) {
        float e = __builtin_exp2f((acc[i][f][jj] - m_) * SCL);
        acc[i][f][jj] = e;
        s_ += e;
      }
#pragma unroll
      for (int off = 1; off < 16; off <<= 1) s_ += __shfl_xor(s_, off, 64);
      inv[i][jj] = 1.f / s_;
    }
  }

  // write P [256 rows][256 cols] f16 @smem[0..131072), swizzled
#pragma unroll
  for (int i = 0; i < 2; ++i)
#pragma unroll
    for (int f = 0; f < 16; ++f)
#pragma unroll
      for (int jj = 0; jj < 4; ++jj) {
        int row = w32 + i * 16 + lg * 4 + jj;
        int colb = (f * 16 + l15) * 2;
        *(f16*)(smem + row * 512 + (colb ^ ((row & 7) << 4))) =
            (f16)(acc[i][f][jj] * inv[i][jj]);
      }

  // ---------- phase B: O = P V over 16 V sub-tiles ----------
  f32x4 oacc[2][16] = {};
#pragma unroll
  for (int st = 0; st < 16; ++st) {
    if (st < 14) {
      stageV(st + 2);
      VMW(2);
    } else if (st == 14) {
      VMW(1);
    } else {
      VMW(0);
    }
    barrier_fenced();
    const int t = st >> 1, dh = st & 1;
    f16x8 pf[2];
#pragma unroll
    for (int i = 0; i < 2; ++i) {
      int row = w32 + i * 16 + l15;
      pf[i] = *(const f16x8*)(smem + row * 512 +
                              ((t * 64 + lg * 16) ^ ((row & 7) << 4)));
    }
    __builtin_amdgcn_s_setprio(1);
#pragma unroll
    for (int jj = 0; jj < 8; ++jj) {
      f16x8 b = ldV(st, jj * 16 + l15, lg * 16);
      const int j = dh * 8 + jj;
#pragma unroll
      for (int i = 0; i < 2; ++i)
        oacc[i][j] =
            __builtin_amdgcn_mfma_f32_16x16x32_f16(pf[i], b, oacc[i][j], 0, 0, 0);
    }
    __builtin_amdgcn_s_setprio(0);
  }

  // write O tile into the Q slice (aliased; this block's Q reads are done)
#pragma unroll
  for (int i = 0; i < 2; ++i)
#pragma unroll
    for (int f = 0; f < 16; ++f)
#pragma unroll
      for (int jj = 0; jj < 4; ++jj) {
        int q = w32 + i * 16 + lg * 4 + jj;
        int d = f * 16 + l15;
        Ow[base + (long)q * 256 + d] = (f16)(oacc[i][f][jj]);
      }
}

// ---------------- launch ----------------
// ws layout (bytes):
//   xb    @ 0         8388608   fp16 x [16384][256]
//   WqT   @ 8388608   1048576   [2048][256] permuted-transposed   (contiguous
//   WkT   @ 9437184   1048576    with WqT -> fused QK B operand [4096][256])
//   WvT   @ 10485760  1048576
//   WoT   @ 11534336  1048576   [256][2048] permuted-transposed
//   bqp   @ 12582912  8192      (contiguous with bkp -> fused bias [4096])
//   bkp   @ 12591104  8192
//   bvp   @ 12599296  8192
//   QK    @ 12607488  134217728 interleaved [bc][qk][h][q][d] f16
//            qk=0 half: Q, overwritten in place by attn O
//            qk=1 half: K; dead after attn -> reused for O-proj fp32 partials
//   VT    @ +134217728 67108864 [bc][h][d][q] f16
extern "C" void kernel_launch(void* const* d_in, const int* in_sizes, int n_in,
                              void* d_out, int out_size, void* d_ws,
                              size_t ws_size, hipStream_t stream) {
  const float* x = (const float*)d_in[0];
  const float* Wq = (const float*)d_in[1];
  const float* bq = (const float*)d_in[2];
  const float* Wk = (const float*)d_in[3];
  const float* bk = (const float*)d_in[4];
  const float* Wv = (const float*)d_in[5];
  const float* bv = (const float*)d_in[6];
  const float* Wo = (const float*)d_in[7];
  const float* bo = (const float*)d_in[8];

  char* ws = (char*)d_ws;
  f16* xb = (f16*)(ws + 0);
  f16* WqT = (f16*)(ws + 8388608);
  f16* WkT = (f16*)(ws + 9437184);
  f16* WvT = (f16*)(ws + 10485760);
  f16* WoT = (f16*)(ws + 11534336);
  float* bqp = (float*)(ws + 12582912);
  float* bkp = (float*)(ws + 12591104);
  float* bvp = (float*)(ws + 12599296);
  f16* QKws = (f16*)(ws + 12607488);
  f16* VTs = (f16*)(ws + 12607488 + 134217728L);
  // O-proj fp32 partials live in the dead K half (qk=1) of QK ws
  float* Opart = (float*)(ws + 12607488 + 1048576);  // per-bc stride 524288 f32
  if (ws_size < 12607488ull + 134217728ull + 67108864ull) return;  // ~204MB

  prep_x<<<4096, 256, 0, stream>>>(x, xb);
  prep_w<<<2048, 256, 0, stream>>>(Wq, Wk, Wv, Wo, bq, bk, bv, WqT, WkT, WvT,
                                   WoT, bqp, bkp, bvp);

  // fused Q+K projection: M=16384 tokens, N=4096 (qk*2048 + h*256 + d), K=256
  gemm256<0><<<1024, 512, 0, stream>>>(xb, WqT, bqp, QKws, 16, 65536, 1048576L,
                                       65536L);
  // V projection, swapped operands -> V^T per head: M=2048 (n'), N=16384 tokens
  gemm256<1><<<512, 512, 0, stream>>>(WvT, xb, bvp, VTs, 64, 65536, 65536L,
                                      524288L);

  attn_fused4<<<dim3(8, 64), 512, 0, stream>>>(QKws, VTs, QKws);

  // output projection, split-K=2 (1024 each): M=16384, N=256, fp32 partials
  gemm128<3><<<dim3(2, 128, 2), 256, 0, stream>>>(QKws, WoT, nullptr, Opart,
                                                  1024, 1048576, 65536, 2048,
                                                  524288L, 0L);
  // partial0 + partial1 + bo -> d_out
  reduce_out<<<4096, 256, 0, stream>>>(Opart, bo, (float*)d_out);
}